// Round 10
// baseline (478.270 us; speedup 1.0000x reference)
//
#include <hip/hip_runtime.h>
#include <hip/hip_bf16.h>
#include <hip/hip_cooperative_groups.h>
#include <math.h>

namespace cg = cooperative_groups;

// Problem constants
#define B_  32
#define S_  512
#define H_  768
#define W_  128
#define G_  4
#define LW  129          // W+1
#define NH_ 4
#define HD_ 192
#define FF_ 2048
#define NL_ 2
#define NLAB_ 6
#define M_   (B_ * LW)   // 4128 rows of x
#define MPAD 4224        // 33 * 128 — zero GEMM bounds checks
#define EPS_ 1e-5f
#define SCALE_ 0.07216878364870323f   // 1/sqrt(192)

// attention padded dims (layer-0 full attention)
#define TP 192           // padded query rows per (b,h)
#define KP 160           // padded key count (mult of 32)
#define KR 144           // staged key rows (9 n-tiles)
#define KLD 200          // LDS row stride for K stage (bank-friendly)
#define PLD 168          // LDS row stride for P (bank-friendly for b128 frag reads)

#define QW_SZ (3 * H_ * H_)   // 1769472
#define OW_SZ (H_ * H_)       // 589824
#define F1_SZ (FF_ * H_)      // 1572864
#define F2_SZ (H_ * FF_)      // 1572864
#define WL_SZ (QW_SZ + OW_SZ + F1_SZ + F2_SZ)  // 5505024

typedef __bf16 bf16_8 __attribute__((ext_vector_type(8)));
typedef float  f32x4  __attribute__((ext_vector_type(4)));
typedef unsigned short ushort8_t __attribute__((ext_vector_type(8)));

__device__ __forceinline__ float b2f(unsigned short u) {
    union { unsigned int i; float f; } c; c.i = ((unsigned int)u) << 16; return c.f;
}
__device__ __forceinline__ unsigned short f2b(float f) {
    union { float f; unsigned int u; } c; c.f = f;
    unsigned int u = c.u;
    return (unsigned short)((u + 0x7FFFu + ((u >> 16) & 1u)) >> 16);   // RNE
}

// ---------------- reductions ----------------
__device__ __forceinline__ float wave_sum(float v) {
#pragma unroll
    for (int off = 1; off < 64; off <<= 1) v += __shfl_xor(v, off, 64);
    return v;
}
__device__ __forceinline__ float wave_max(float v) {
#pragma unroll
    for (int off = 1; off < 64; off <<= 1) v = fmaxf(v, __shfl_xor(v, off, 64));
    return v;
}
__device__ __forceinline__ float block_sum(float v, float* red) {
    v = wave_sum(v);
    int wid = threadIdx.x >> 6, lane = threadIdx.x & 63;
    if (lane == 0) red[wid] = v;
    __syncthreads();
    float r = (red[0] + red[1]) + (red[2] + red[3]);
    __syncthreads();
    return r;
}

// ---------------- R15: fused gather+pool AND weight cvt (one launch, both BW-bound) ----------------
__global__ __launch_bounds__(256) void build_cvt_kernel(
    const float* __restrict__ hidden,   // (B,S,H)
    const int*   __restrict__ wti,      // (B,W,G)
    const int*   __restrict__ gmask,    // (B,W,G)
    const int*   __restrict__ wvalid,   // (B,W)
    unsigned short* __restrict__ xb,    // (MPAD,H) bf16
    const float4* __restrict__ qw, const float4* __restrict__ ow,
    const float4* __restrict__ f1, const float4* __restrict__ f2,
    ushort4* __restrict__ dst)          // wb
{
    int bx = blockIdx.x;
    int tid = threadIdx.x;
    constexpr int NGATHER = (LW + 3) * B_;
    if (bx >= NGATHER) {
        // ---- weight fp32 -> bf16 ----
        constexpr int WL4 = WL_SZ / 4;
        int i = (bx - NGATHER) * 256 + tid;   // 0 .. 2*WL4
        int l = (i < WL4) ? 0 : 1;
        int j = i - l * WL4;
        float4 v;
        if (j < QW_SZ / 4)                          v = qw[l * (QW_SZ / 4) + j];
        else if (j < (QW_SZ + OW_SZ) / 4)           v = ow[l * (OW_SZ / 4) + j - QW_SZ / 4];
        else if (j < (QW_SZ + OW_SZ + F1_SZ) / 4)   v = f1[l * (F1_SZ / 4) + j - (QW_SZ + OW_SZ) / 4];
        else                                        v = f2[l * (F2_SZ / 4) + j - (QW_SZ + OW_SZ + F1_SZ) / 4];
        ushort4 o; o.x = f2b(v.x); o.y = f2b(v.y); o.z = f2b(v.z); o.w = f2b(v.w);
        dst[i] = o;
        return;
    }
    // ---- gather + masked mean pool -> xb (incl. pad-row zeroing) ----
    int t = bx % (LW + 3);
    int b = bx / (LW + 3);
    if (t >= LW) {
        int pr = M_ + b * 3 + (t - LW);
        size_t xo = (size_t)pr * H_;
#pragma unroll
        for (int i = 0; i < 3; i++) xb[xo + tid + i * 256] = 0;
        return;
    }
    size_t xo = ((size_t)b * LW + t) * H_;
    if (t == 0) {
        const float* src = hidden + (size_t)b * S_ * H_;   // token 0
#pragma unroll
        for (int i = 0; i < 3; i++) xb[xo + tid + i * 256] = f2b(src[tid + i * 256]);
    } else {
        int w = t - 1;
        int valid = wvalid[b * W_ + w];
        int ids[G_]; float msk[G_]; float cnt = 0.f;
#pragma unroll
        for (int g = 0; g < G_; g++) {
            ids[g] = wti[(b * W_ + w) * G_ + g];
            msk[g] = (gmask[(b * W_ + w) * G_ + g] != 0) ? 1.f : 0.f;
            cnt += msk[g];
        }
        float inv = valid ? (1.f / fmaxf(cnt, 1.f)) : 0.f;
#pragma unroll
        for (int i = 0; i < 3; i++) {
            int c = tid + i * 256;
            float a = 0.f;
#pragma unroll
            for (int g = 0; g < G_; g++)
                a += msk[g] * hidden[((size_t)b * S_ + ids[g]) * H_ + c];
            xb[xo + c] = f2b(a * inv);
        }
    }
}

// ---------------- LDS-staged bf16 MFMA GEMM body (shared by all GEMM kernels) ----------------
// XOR chunk swizzle (R6-verified). ldc: output leading dim. lda: A leading dim
// (CLS q-proj uses lda=LW*H to hit CLS rows). Pad rows read workspace junk; MFMA
// rows are row-local so junk stays in unread output rows.
template <int BM, int BN, int BK, int RELU, int OUTBF>
__device__ __forceinline__ void gemm_body(
    unsigned short* As, unsigned short* Bs,
    const unsigned short* __restrict__ A,   // (rows,lda) bf16
    const unsigned short* __restrict__ Bw,  // (N,K) bf16
    const float* __restrict__ bias,         // (N) f32
    void* __restrict__ Cout,                // (rows,ldc) f32 or bf16
    int N, int K, int ldc, int lda, int bm, int bn)
{
    constexpr int MI  = BM / 32;
    constexpr int NJ  = BN / 32;
    constexpr int CPR = BK / 8;
    constexpr int RPL = 2048 / BK;
    constexpr int SA  = BM * BK / 2048;
    constexpr int SB  = BN * BK / 2048;

    const int tid  = threadIdx.x;
    const int lane = tid & 63;
    const int wid  = tid >> 6;

    const int wm = (wid & 1) * (BM / 2);
    const int wn = (wid >> 1) * (BN / 2);
    const int r  = lane & 15;
    const int q8 = lane >> 4;
    const int m8 = r & (CPR - 1);

    const int srow = tid / CPR;
    const int scol = (tid % CPR) ^ (srow & (CPR - 1));
    const unsigned short* Ag = A  + (size_t)(bm + srow) * lda + scol * 8;
    const unsigned short* Bg = Bw + (size_t)(bn + srow) * K + scol * 8;

    const bf16_8* Af = (const bf16_8*)As;
    const bf16_8* Bf = (const bf16_8*)Bs;
    int arow[MI], brow[NJ];
#pragma unroll
    for (int i = 0; i < MI; i++) arow[i] = (wm + i * 16 + r) * CPR;
#pragma unroll
    for (int j = 0; j < NJ; j++) brow[j] = (wn + j * 16 + r) * CPR;

    f32x4 acc[MI][NJ];
#pragma unroll
    for (int i = 0; i < MI; i++)
#pragma unroll
        for (int j = 0; j < NJ; j++) acc[i][j] = (f32x4){0.f, 0.f, 0.f, 0.f};

    for (int k0 = 0; k0 < K; k0 += BK) {
#pragma unroll
        for (int s = 0; s < SA; s++)
            __builtin_amdgcn_global_load_lds(
                (const __attribute__((address_space(1))) void*)(Ag + (size_t)(s * RPL) * lda + k0),
                (__attribute__((address_space(3))) void*)(As + s * 2048 + tid * 8), 16, 0, 0);
#pragma unroll
        for (int s = 0; s < SB; s++)
            __builtin_amdgcn_global_load_lds(
                (const __attribute__((address_space(1))) void*)(Bg + (size_t)(s * RPL) * K + k0),
                (__attribute__((address_space(3))) void*)(Bs + s * 2048 + tid * 8), 16, 0, 0);
        __syncthreads();
#pragma unroll
        for (int ks = 0; ks < BK / 32; ks++) {
            const int cc = (ks * 4 + q8) ^ m8;
            bf16_8 a[MI], b[NJ];
#pragma unroll
            for (int i = 0; i < MI; i++) a[i] = Af[arow[i] + cc];
#pragma unroll
            for (int j = 0; j < NJ; j++) b[j] = Bf[brow[j] + cc];
#pragma unroll
            for (int i = 0; i < MI; i++)
#pragma unroll
                for (int j = 0; j < NJ; j++)
                    acc[i][j] = __builtin_amdgcn_mfma_f32_16x16x32_bf16(a[i], b[j], acc[i][j], 0, 0, 0);
        }
        __syncthreads();
    }

    int col[NJ]; float bv[NJ];
#pragma unroll
    for (int j = 0; j < NJ; j++) { col[j] = bn + wn + j * 16 + r; bv[j] = bias[col[j]]; }
    const int row0 = bm + wm + ((lane >> 4) << 2);
#pragma unroll
    for (int i = 0; i < MI; i++) {
#pragma unroll
        for (int rg = 0; rg < 4; rg++) {
            size_t rowoff = (size_t)(row0 + i * 16 + rg) * ldc;
#pragma unroll
            for (int j = 0; j < NJ; j++) {
                float v = acc[i][j][rg] + bv[j];
                if (RELU) v = fmaxf(v, 0.f);
                if (OUTBF) ((unsigned short*)Cout)[rowoff + col[j]] = f2b(v);
                else       ((float*)Cout)[rowoff + col[j]] = v;
            }
        }
    }
}

// ---------------- generic GEMM kernel (tiles = R0/R7-verified configs) ----------------
template <int BM, int BN, int BK, int RELU, int OUTBF, int SWZ>
__global__ __launch_bounds__(256) void gemm_mfma(
    const unsigned short* __restrict__ A,
    const unsigned short* __restrict__ Bw,
    const float* __restrict__ bias,
    void* __restrict__ Cout,
    int N, int K, int ldc, int lda)
{
    __shared__ __align__(16) unsigned short As[BM * BK];
    __shared__ __align__(16) unsigned short Bs[BN * BK];
    int bx = blockIdx.x, by = blockIdx.y;
    if (SWZ) {
        int nx = gridDim.x;
        int total = nx * gridDim.y;              // must be % 8 == 0
        int id = by * nx + bx;
        int id2 = (id & 7) * (total >> 3) + (id >> 3);
        by = id2 / nx; bx = id2 - by * nx;
    }
    gemm_body<BM, BN, BK, RELU, OUTBF>(As, Bs, A, Bw, bias, Cout, N, K, ldc, lda,
                                       by * BM, bx * BN);
}

// ---------------- R17: layer-1 KV GEMM + CLS q-proj in ONE launch ----------------
// grid (13,66): bx<12 = KV tiles (swizzled over 792), bx==12 & by<6 = q-proj tiles.
__global__ __launch_bounds__(256) void gemm_kv_q_kernel(
    const unsigned short* __restrict__ xb,
    const unsigned short* __restrict__ wkv,   // layer-1 qkv_w rows 768..2303 (K,V)
    const float* __restrict__ bkv,            // qkv_b + 3H + H
    unsigned short* __restrict__ kvout,       // qkvb + H (ldc = 3H)
    const unsigned short* __restrict__ wq,    // layer-1 qkv_w rows 0..767 (Q)
    const float* __restrict__ qb,             // qkv_b + 3H
    unsigned short* __restrict__ qrows)       // (64,H)
{
    __shared__ __align__(16) unsigned short As[64 * 64];
    __shared__ __align__(16) unsigned short Bs[128 * 64];
    int bx = blockIdx.x, by = blockIdx.y;
    if (bx == 12) {
        if (by >= 6) return;
        // q = CLS rows @ Wq^T + qb  (A strided by LW*H to hit CLS rows; bm=0)
        gemm_body<64, 128, 64, 0, 1>(As, Bs, xb, wq, qb, qrows,
                                     H_, H_, H_, LW * H_, 0, by * 128);
        return;
    }
    int id = by * 12 + bx;
    int id2 = (id & 7) * (792 >> 3) + (id >> 3);
    by = id2 / 12; bx = id2 - by * 12;
    gemm_body<64, 128, 64, 0, 1>(As, Bs, xb, wkv, bkv, kvout,
                                 2 * H_, H_, 3 * H_, H_, by * 64, bx * 128);
}

// ---------------- V transpose: qkvb V-third -> Vt[bh][192][KP] bf16 (zero-padded) ----------------
__global__ __launch_bounds__(256) void vt_kernel(
    const unsigned short* __restrict__ qkv,  // (MPAD, 3H)
    unsigned short* __restrict__ vtb)        // (128, HD_, KP)
{
    __shared__ __align__(16) unsigned short Vs[KR * KLD];
    int bh = blockIdx.x;
    int b = bh >> 2, h = bh & 3;
    int tid = threadIdx.x;
    for (int c = tid; c < KR * 24; c += 256) {
        int t = c / 24, j = c - t * 24;
        ushort8_t v = (ushort8_t){0,0,0,0,0,0,0,0};
        if (t < LW)
            v = *(const ushort8_t*)(qkv + (size_t)(b * LW + t) * (3 * H_) + 2 * H_ + h * HD_ + j * 8);
        *(ushort8_t*)(&Vs[t * KLD + j * 8]) = v;
    }
    __syncthreads();
    size_t obase = (size_t)bh * (HD_ * KP);
    for (int c = tid; c < HD_ * (KP / 4); c += 256) {
        int d = c / (KP / 4), t0 = (c - d * (KP / 4)) * 4;
        ushort4 o;
        o.x = (t0 + 0 < KR) ? Vs[(t0 + 0) * KLD + d] : 0;
        o.y = (t0 + 1 < KR) ? Vs[(t0 + 1) * KLD + d] : 0;
        o.z = (t0 + 2 < KR) ? Vs[(t0 + 2) * KLD + d] : 0;
        o.w = (t0 + 3 < KR) ? Vs[(t0 + 3) * KLD + d] : 0;
        *(ushort4*)(&vtb[obase + (size_t)d * KP + t0]) = o;
    }
}

// ---------------- fused scores+softmax+PV: P stays in LDS (layer-0 full attention) ----------------
// R17: mb==2 tile covers rows 128..191 but only row 128 is real — skip dead work.
__global__ __launch_bounds__(256) void attn_fused_kernel(
    const unsigned short* __restrict__ qkv,   // (MPAD, 3H)
    const int*            __restrict__ wvalid,
    const unsigned short* __restrict__ vtb,   // (128, HD_, KP)
    unsigned short*       __restrict__ ctx)   // (MPAD, H)
{
    __shared__ __align__(16) unsigned short Ks[KR * KLD];
    __shared__ __align__(16) unsigned short Ps[64 * PLD];
    __shared__ float msk[KR];
    int mb = blockIdx.x;          // 0..2
    int bh = blockIdx.y;
    int b = bh >> 2, h = bh & 3;
    int tid = threadIdx.x, lane = tid & 63, wid = tid >> 6;
    int q = lane >> 4, r = lane & 15;

    for (int c = tid; c < KR * 24; c += 256) {
        int t = c / 24, j = c - t * 24;
        ushort8_t v = (ushort8_t){0,0,0,0,0,0,0,0};
        if (t < LW)
            v = *(const ushort8_t*)(qkv + (size_t)(b * LW + t) * (3 * H_) + H_ + h * HD_ + j * 8);
        *(ushort8_t*)(&Ks[t * KLD + j * 8]) = v;
    }
    if (tid < KR) {
        bool valid = (tid == 0) || (tid <= W_ && wvalid[b * W_ + tid - 1] != 0);
        msk[tid] = valid ? 0.f : -1e30f;
    }
    __syncthreads();

    // ---- phase 1: scores + softmax, one 16-row tile per wave ----
    const int lrow0 = wid * 16;
    const bool p1_active = (mb < 2) || (lrow0 == 0);
    if (p1_active) {
        const unsigned short* Qp = qkv + ((size_t)(b * LW) + mb * 64 + lrow0 + r) * (3 * H_) + h * HD_;
        f32x4 acc[9];
#pragma unroll
        for (int nt = 0; nt < 9; nt++) acc[nt] = (f32x4){0.f, 0.f, 0.f, 0.f};
        for (int ks = 0; ks < HD_ / 32; ks++) {
            bf16_8 a = *(const bf16_8*)(Qp + ks * 32 + q * 8);
#pragma unroll
            for (int nt = 0; nt < 9; nt++) {
                bf16_8 bfrag = *(const bf16_8*)(&Ks[(nt * 16 + r) * KLD + ks * 32 + q * 8]);
                acc[nt] = __builtin_amdgcn_mfma_f32_16x16x32_bf16(a, bfrag, acc[nt], 0, 0, 0);
            }
        }
        float mk[9];
#pragma unroll
        for (int nt = 0; nt < 9; nt++) mk[nt] = msk[nt * 16 + r];
#pragma unroll
        for (int rg = 0; rg < 4; rg++) {
            float v[9]; float mx = -1e30f;
#pragma unroll
            for (int nt = 0; nt < 9; nt++) { v[nt] = acc[nt][rg] * SCALE_ + mk[nt]; mx = fmaxf(mx, v[nt]); }
#pragma unroll
            for (int off = 1; off < 16; off <<= 1) mx = fmaxf(mx, __shfl_xor(mx, off, 64));
            float s = 0.f;
#pragma unroll
            for (int nt = 0; nt < 9; nt++) { v[nt] = __expf(v[nt] - mx); s += v[nt]; }
#pragma unroll
            for (int off = 1; off < 16; off <<= 1) s += __shfl_xor(s, off, 64);
            float inv = 1.f / s;
            int lr = lrow0 + q * 4 + rg;
#pragma unroll
            for (int nt = 0; nt < 9; nt++)
                Ps[lr * PLD + nt * 16 + r] = f2b(v[nt] * inv);
            Ps[lr * PLD + KR + r] = 0;   // zero pad cols 144..159
        }
    }
    __syncthreads();

    // ---- phase 2: ctx = P @ V^T; waves 2m x 2n (32m x 96n each) ----
    const int wm = (wid & 1) * 32, wn = (wid >> 1) * 96;
    if (!(mb == 2 && wm == 32)) {
        size_t vbase = (size_t)bh * (HD_ * KP);
        f32x4 pacc[2][6];
#pragma unroll
        for (int i = 0; i < 2; i++)
#pragma unroll
            for (int j = 0; j < 6; j++) pacc[i][j] = (f32x4){0.f, 0.f, 0.f, 0.f};

        for (int ks = 0; ks < KP / 32; ks++) {
            bf16_8 a[2], bb[6];
#pragma unroll
            for (int i = 0; i < 2; i++)
                a[i] = *(const bf16_8*)(&Ps[(wm + i * 16 + r) * PLD + ks * 32 + q * 8]);
#pragma unroll
            for (int j = 0; j < 6; j++)
                bb[j] = *(const bf16_8*)(vtb + vbase + (size_t)(wn + j * 16 + r) * KP + ks * 32 + q * 8);
#pragma unroll
            for (int i = 0; i < 2; i++)
#pragma unroll
                for (int j = 0; j < 6; j++)
                    pacc[i][j] = __builtin_amdgcn_mfma_f32_16x16x32_bf16(a[i], bb[j], pacc[i][j], 0, 0, 0);
        }

#pragma unroll
        for (int i = 0; i < 2; i++) {
#pragma unroll
            for (int rg = 0; rg < 4; rg++) {
                int tl = mb * 64 + wm + i * 16 + q * 4 + rg;
                if (tl < LW) {
                    size_t rowoff = (size_t)(b * LW + tl) * H_ + h * HD_;
#pragma unroll
                    for (int j = 0; j < 6; j++)
                        ctx[rowoff + wn + j * 16 + r] = f2b(pacc[i][j][rg]);
                }
            }
        }
    }
}

// ---------------- fused residual add + LayerNorm (pure bf16 stream, f32 math) ----------------
__global__ __launch_bounds__(256) void add_ln_kernel(
    unsigned short* __restrict__ xb, const unsigned short* __restrict__ res,
    const float* __restrict__ sc, const float* __restrict__ bi)
{
    __shared__ float red[4];
    int row = blockIdx.x;
    int tid = threadIdx.x;
    size_t base = (size_t)row * H_;
    float v[3];
    float sum = 0.f;
#pragma unroll
    for (int i = 0; i < 3; i++) {
        int c = tid + i * 256;
        float t = b2f(xb[base + c]) + b2f(res[base + c]);
        v[i] = t; sum += t;
    }
    sum = block_sum(sum, red);
    float mean = sum * (1.f / H_);
    float var = 0.f;
#pragma unroll
    for (int i = 0; i < 3; i++) { float d = v[i] - mean; var += d * d; }
    var = block_sum(var, red);
    float inv = rsqrtf(var * (1.f / H_) + EPS_);
#pragma unroll
    for (int i = 0; i < 3; i++) {
        int c = tid + i * 256;
        xb[base + c] = f2b((v[i] - mean) * inv * sc[c] + bi[c]);
    }
}

// ---------------- R19: fused layer-1 tail — cooperative launch, cg grid sync ----------------
// grid = 128 blocks, launched via hipLaunchCooperativeKernel (guaranteed co-residency).
// A: attn core per (b,h) | B: out-proj 6 tiles | C: LN1 32 | D: ff1 16 tiles | E: ff2 6 | F: final 32
__global__ __launch_bounds__(256) void cls_tail_fused_kernel(
    const unsigned short* __restrict__ qrows,  // (64,H): rows 0..31 valid
    const unsigned short* __restrict__ qkvb,   // (MPAD,3H): cols 768..2303 = K,V
    const int* __restrict__ wvalid,
    const unsigned short* __restrict__ xb,     // residual CLS rows
    const unsigned short* __restrict__ wo, const float* __restrict__ ob,
    const float* __restrict__ ln1s, const float* __restrict__ ln1b,
    const unsigned short* __restrict__ f1w, const float* __restrict__ f1b,
    const unsigned short* __restrict__ f2w, const float* __restrict__ f2bias,
    const float* __restrict__ ln2s, const float* __restrict__ ln2b,
    const float* __restrict__ cls_w, const float* __restrict__ cls_b,
    unsigned short* __restrict__ ctxc, unsigned short* __restrict__ xc64,
    unsigned short* __restrict__ tmp64, unsigned short* __restrict__ h1c,
    float* __restrict__ out)
{
    __shared__ __align__(16) unsigned short As[64 * 64];
    __shared__ __align__(16) unsigned short Bs[128 * 64];
    __shared__ float qh[HD_];
    __shared__ float sr[160];
    __shared__ float ps[LW];
    __shared__ float red[4];
    __shared__ float lred[4][NLAB_];
    cg::grid_group grid = cg::this_grid();
    const int blk = blockIdx.x;   // 0..127
    const int tid = threadIdx.x, lane = tid & 63, wid = tid >> 6;

    // ---- phase A: attention core (all 128 blocks; blk = b*4+h) ----
    {
        int b = blk >> 2, h = blk & 3;
        if (tid < HD_) qh[tid] = b2f(qrows[(size_t)b * H_ + h * HD_ + tid]);
        __syncthreads();
        int grp = tid >> 3, s8 = tid & 7;
#pragma unroll
        for (int p = 0; p < 5; p++) {
            int t = p * 32 + grp;
            float acc = 0.f;
            if (t < LW) {
                const unsigned short* kr = qkvb + (size_t)(b * LW + t) * (3 * H_) + H_ + h * HD_ + s8 * 24;
#pragma unroll
                for (int j = 0; j < 3; j++) {
                    ushort8_t k8 = *(const ushort8_t*)(kr + j * 8);
#pragma unroll
                    for (int jj = 0; jj < 8; jj++) acc += qh[s8 * 24 + j * 8 + jj] * b2f(k8[jj]);
                }
            }
            acc += __shfl_xor(acc, 1, 64);
            acc += __shfl_xor(acc, 2, 64);
            acc += __shfl_xor(acc, 4, 64);
            if (s8 == 0 && t < LW) {
                bool valid = (t == 0) || (wvalid[b * W_ + t - 1] != 0);
                sr[t] = valid ? acc * SCALE_ : -1e30f;
            }
        }
        __syncthreads();
        float sc = (tid < LW) ? sr[tid] : -1e30f;
        float mx = wave_max(sc);
        if (lane == 0) red[wid] = mx;
        __syncthreads();
        mx = fmaxf(fmaxf(red[0], red[1]), fmaxf(red[2], red[3]));
        __syncthreads();
        float e = (tid < LW) ? __expf(sc - mx) : 0.f;
        float ssum = wave_sum(e);
        if (lane == 0) red[wid] = ssum;
        __syncthreads();
        ssum = (red[0] + red[1]) + (red[2] + red[3]);
        if (tid < LW) ps[tid] = e * (1.f / ssum);
        __syncthreads();
        if (tid < HD_) {
            const unsigned short* vb = qkvb + (size_t)(b * LW) * (3 * H_) + 2 * H_ + h * HD_ + tid;
            float cx = 0.f;
#pragma unroll 8
            for (int t = 0; t < LW; t++)
                cx += ps[t] * b2f(vb[(size_t)t * (3 * H_)]);
            ctxc[(size_t)b * H_ + h * HD_ + tid] = f2b(cx);
        }
    }
    grid.sync();

    // ---- phase B: out-proj (blocks 0..5, 64x128 MFMA tiles) ----
    if (blk < 6)
        gemm_body<64, 128, 64, 0, 1>(As, Bs, ctxc, wo, ob, tmp64, H_, H_, H_, H_, 0, blk * 128);
    grid.sync();

    // ---- phase C: LN1 (blocks 0..31; residual from xb CLS rows) ----
    if (blk < B_) {
        int b = blk;
        float v[3]; float sum = 0.f;
#pragma unroll
        for (int i = 0; i < 3; i++) {
            int c = tid + i * 256;
            float t = b2f(tmp64[(size_t)b * H_ + c]) + b2f(xb[(size_t)(b * LW) * H_ + c]);
            v[i] = t; sum += t;
        }
        sum = block_sum(sum, red);
        float mean = sum * (1.f / H_);
        float var = 0.f;
#pragma unroll
        for (int i = 0; i < 3; i++) { float d = v[i] - mean; var += d * d; }
        var = block_sum(var, red);
        float inv = rsqrtf(var * (1.f / H_) + EPS_);
#pragma unroll
        for (int i = 0; i < 3; i++) {
            int c = tid + i * 256;
            xc64[(size_t)b * H_ + c] = f2b((v[i] - mean) * inv * ln1s[c] + ln1b[c]);
        }
    }
    grid.sync();

    // ---- phase D: ff1 + relu (blocks 0..15) ----
    if (blk < 16)
        gemm_body<64, 128, 64, 1, 1>(As, Bs, xc64, f1w, f1b, h1c, FF_, H_, FF_, H_, 0, blk * 128);
    grid.sync();

    // ---- phase E: ff2 (blocks 0..5) ----
    if (blk < 6)
        gemm_body<64, 128, 64, 0, 1>(As, Bs, h1c, f2w, f2bias, tmp64, H_, FF_, H_, FF_, 0, blk * 128);
    grid.sync();

    // ---- phase F: LN2 + pooled + logits (blocks 0..31) ----
    if (blk < B_) {
        int b = blk;
        size_t base = (size_t)b * H_;
        float v[3]; float sum = 0.f;
#pragma unroll
        for (int i = 0; i < 3; i++) {
            int c = tid + i * 256;
            float t = b2f(tmp64[base + c]) + b2f(xc64[base + c]);
            v[i] = t; sum += t;
        }
        sum = block_sum(sum, red);
        float mean = sum * (1.f / H_);
        float var = 0.f;
#pragma unroll
        for (int i = 0; i < 3; i++) { float d = v[i] - mean; var += d * d; }
        var = block_sum(var, red);
        float rinv = rsqrtf(var * (1.f / H_) + EPS_);
        float f3[3];
#pragma unroll
        for (int i = 0; i < 3; i++) {
            int c = tid + i * 256;
            f3[i] = (v[i] - mean) * rinv * ln2s[c] + ln2b[c];
            out[B_ * NLAB_ + b * H_ + c] = f3[i];
        }
        float l6[NLAB_] = {0.f, 0.f, 0.f, 0.f, 0.f, 0.f};
#pragma unroll
        for (int i = 0; i < 3; i++) {
            int c = tid + i * 256;
#pragma unroll
            for (int w = 0; w < NLAB_; w++) l6[w] += f3[i] * cls_w[w * H_ + c];
        }
#pragma unroll
        for (int w = 0; w < NLAB_; w++) l6[w] = wave_sum(l6[w]);
        if (lane == 0) {
#pragma unroll
            for (int w = 0; w < NLAB_; w++) lred[wid][w] = l6[w];
        }
        __syncthreads();
        if (tid < NLAB_)
            out[b * NLAB_ + tid] = lred[0][tid] + lred[1][tid] + lred[2][tid] + lred[3][tid] + cls_b[tid];
    }
}

extern "C" void kernel_launch(void* const* d_in, const int* in_sizes, int n_in,
                              void* d_out, int out_size, void* d_ws, size_t ws_size,
                              hipStream_t stream) {
    const float* hidden = (const float*)d_in[0];
    const int*   wti    = (const int*)d_in[1];
    const int*   gmask  = (const int*)d_in[2];
    const int*   wvalid = (const int*)d_in[3];
    const float* qkv_w  = (const float*)d_in[4];
    const float* qkv_b  = (const float*)d_in[5];
    const float* out_w  = (const float*)d_in[6];
    const float* out_b  = (const float*)d_in[7];
    const float* ff1_w  = (const float*)d_in[8];
    const float* ff1_b  = (const float*)d_in[9];
    const float* ff2_w  = (const float*)d_in[10];
    const float* ff2_b  = (const float*)d_in[11];
    const float* ln1_s  = (const float*)d_in[12];
    const float* ln1_b  = (const float*)d_in[13];
    const float* ln2_s  = (const float*)d_in[14];
    const float* ln2_b  = (const float*)d_in[15];
    const float* cls_w  = (const float*)d_in[16];
    const float* cls_b  = (const float*)d_in[17];
    float* out = (float*)d_out;

    // workspace (all bf16): ~62 MB (ws_size ~256 MB per fill counters)
    const size_t XSZ = (size_t)MPAD * H_;             // 3,244,032
    const size_t ASZ = (size_t)128 * TP * KP;         // 3,932,160
    const size_t R64 = (size_t)64 * H_;               // 49,152
    unsigned short* U    = (unsigned short*)d_ws;     // ASZ region: vtb/tmpb layer 0; CLS bufs layer 1
    unsigned short* vtb  = U;
    unsigned short* tmpb = U;                         // lifetimes disjoint
    unsigned short* qrows64 = U + 1 * R64;            // (64,H) q projections (rows 32..63 junk)
    unsigned short* ctxc  = U + 2 * R64;              // (64,H) attention context (rows 32..63 junk)
    unsigned short* xc64  = U + 3 * R64;              // (64,H) after LN1 (rows 32..63 junk)
    unsigned short* tmp64 = U + 4 * R64;              // (64,H) proj scratch
    unsigned short* h1c   = U + 5 * R64;              // (64,FF)
    unsigned short* xb   = U + ASZ;                   // XSZ
    unsigned short* ctxb = xb + XSZ;                  // XSZ
    unsigned short* qkvb = ctxb + XSZ;                // 3*XSZ (aliased: h1 MPAD*FF)
    unsigned short* wb   = qkvb + (size_t)MPAD * 3 * H_;     // 2*WL_SZ (both layers)

    // fused gather+pool + weight conversion (one launch)
    build_cvt_kernel<<<(LW + 3) * B_ + 2 * WL_SZ / 4 / 256, 256, 0, stream>>>(
        hidden, wti, gmask, wvalid, xb,
        (const float4*)qkv_w, (const float4*)out_w,
        (const float4*)ff1_w, (const float4*)ff2_w, (ushort4*)wb);

    const int GM = MPAD / 64;   // 66 m-blocks

    // ---------------- layer 0: full transformer block (R0/R7-verified configs) ----------------
    {
        unsigned short* wbl = wb;
        gemm_mfma<64, 128, 64, 0, 1, 0><<<dim3(3 * H_ / 128, GM), 256, 0, stream>>>(
            xb, wbl, qkv_b, qkvb, 3 * H_, H_, 3 * H_, H_);
        vt_kernel<<<128, 256, 0, stream>>>(qkvb, vtb);
        attn_fused_kernel<<<dim3(3, 128), 256, 0, stream>>>(qkvb, wvalid, vtb, ctxb);
        gemm_mfma<64, 64, 64, 0, 1, 1><<<dim3(H_ / 64, GM), 256, 0, stream>>>(
            ctxb, wbl + QW_SZ, out_b, tmpb, H_, H_, H_, H_);
        add_ln_kernel<<<M_, 256, 0, stream>>>(xb, tmpb, ln1_s, ln1_b);
        gemm_mfma<64, 128, 64, 1, 1, 1><<<dim3(FF_ / 128, GM), 256, 0, stream>>>(
            xb, wbl + QW_SZ + OW_SZ, ff1_b, qkvb, FF_, H_, FF_, H_);
        gemm_mfma<64, 64, 64, 0, 1, 1><<<dim3(H_ / 64, GM), 256, 0, stream>>>(
            qkvb, wbl + QW_SZ + OW_SZ + F1_SZ, ff2_b, tmpb, H_, FF_, H_, FF_);
        add_ln_kernel<<<M_, 256, 0, stream>>>(xb, tmpb, ln2_s, ln2_b);
    }

    // ---------------- layer 1: CLS-only path (only x[:,0,:] is read downstream) ----------------
    {
        unsigned short* wbl = wb + WL_SZ;
        // K,V for all rows + CLS q-proj, one launch (grid 13x66)
        gemm_kv_q_kernel<<<dim3(13, GM), 256, 0, stream>>>(
            xb, wbl + (size_t)H_ * H_, qkv_b + 3 * H_ + H_, qkvb + H_,
            wbl, qkv_b + 3 * H_, qrows64);
        // fused tail: attn core -> out-proj -> LN1 -> ff1 -> ff2 -> LN2+logits
        // cooperative launch: guaranteed co-residency for grid.sync()
        const unsigned short* qrows_a = qrows64;
        const unsigned short* qkvb_a  = qkvb;
        const int*            wv_a    = wvalid;
        const unsigned short* xb_a    = xb;
        const unsigned short* wo_a    = wbl + QW_SZ;
        const float*          ob_a    = out_b + H_;
        const float*          l1s_a   = ln1_s + H_;
        const float*          l1b_a   = ln1_b + H_;
        const unsigned short* f1w_a   = wbl + QW_SZ + OW_SZ;
        const float*          f1b_a   = ff1_b + FF_;
        const unsigned short* f2w_a   = wbl + QW_SZ + OW_SZ + F1_SZ;
        const float*          f2b_a   = ff2_b + H_;
        const float*          l2s_a   = ln2_s + H_;
        const float*          l2b_a   = ln2_b + H_;
        const float*          cw_a    = cls_w;
        const float*          cb_a    = cls_b;
        unsigned short*       ctxc_a  = ctxc;
        unsigned short*       xc64_a  = xc64;
        unsigned short*       tmp64_a = tmp64;
        unsigned short*       h1c_a   = h1c;
        float*                out_a   = out;
        void* kargs[] = {
            (void*)&qrows_a, (void*)&qkvb_a, (void*)&wv_a, (void*)&xb_a,
            (void*)&wo_a, (void*)&ob_a, (void*)&l1s_a, (void*)&l1b_a,
            (void*)&f1w_a, (void*)&f1b_a, (void*)&f2w_a, (void*)&f2b_a,
            (void*)&l2s_a, (void*)&l2b_a, (void*)&cw_a, (void*)&cb_a,
            (void*)&ctxc_a, (void*)&xc64_a, (void*)&tmp64_a, (void*)&h1c_a,
            (void*)&out_a
        };
        hipLaunchCooperativeKernel((void*)cls_tail_fused_kernel,
                                   dim3(128), dim3(256), kargs, 0, stream);
    }
    (void)in_sizes; (void)n_in; (void)out_size; (void)ws_size;
}

// Round 11
// 370.350 us; speedup vs baseline: 1.2914x; 1.2914x over previous
//
#include <hip/hip_runtime.h>
#include <hip/hip_bf16.h>
#include <math.h>

// Problem constants
#define B_  32
#define S_  512
#define H_  768
#define W_  128
#define G_  4
#define LW  129          // W+1
#define NH_ 4
#define HD_ 192
#define FF_ 2048
#define NL_ 2
#define NLAB_ 6
#define M_   (B_ * LW)   // 4128 rows of x
#define MPAD 4224        // 33 * 128 — zero GEMM bounds checks
#define EPS_ 1e-5f
#define SCALE_ 0.07216878364870323f   // 1/sqrt(192)

// attention padded dims (layer-0 full attention)
#define TP 192           // padded query rows per (b,h)
#define KP 160           // padded key count (mult of 32)
#define KR 144           // staged key rows (9 n-tiles)
#define KLD 200          // LDS row stride for K stage (bank-friendly)
#define PLD 168          // LDS row stride for P (bank-friendly for b128 frag reads)

#define QW_SZ (3 * H_ * H_)   // 1769472
#define OW_SZ (H_ * H_)       // 589824
#define F1_SZ (FF_ * H_)      // 1572864
#define F2_SZ (H_ * FF_)      // 1572864
#define WL_SZ (QW_SZ + OW_SZ + F1_SZ + F2_SZ)  // 5505024

typedef __bf16 bf16_8 __attribute__((ext_vector_type(8)));
typedef float  f32x4  __attribute__((ext_vector_type(4)));
typedef unsigned short ushort8_t __attribute__((ext_vector_type(8)));

__device__ __forceinline__ float b2f(unsigned short u) {
    union { unsigned int i; float f; } c; c.i = ((unsigned int)u) << 16; return c.f;
}
__device__ __forceinline__ unsigned short f2b(float f) {
    union { float f; unsigned int u; } c; c.f = f;
    unsigned int u = c.u;
    return (unsigned short)((u + 0x7FFFu + ((u >> 16) & 1u)) >> 16);   // RNE
}

// ---------------- reductions ----------------
__device__ __forceinline__ float wave_sum(float v) {
#pragma unroll
    for (int off = 1; off < 64; off <<= 1) v += __shfl_xor(v, off, 64);
    return v;
}
__device__ __forceinline__ float wave_max(float v) {
#pragma unroll
    for (int off = 1; off < 64; off <<= 1) v = fmaxf(v, __shfl_xor(v, off, 64));
    return v;
}
__device__ __forceinline__ float block_sum(float v, float* red) {
    v = wave_sum(v);
    int wid = threadIdx.x >> 6, lane = threadIdx.x & 63;
    if (lane == 0) red[wid] = v;
    __syncthreads();
    float r = (red[0] + red[1]) + (red[2] + red[3]);
    __syncthreads();
    return r;
}

// ---------------- R15: fused gather+pool AND weight cvt (one launch, both BW-bound) ----------------
__global__ __launch_bounds__(256) void build_cvt_kernel(
    const float* __restrict__ hidden,   // (B,S,H)
    const int*   __restrict__ wti,      // (B,W,G)
    const int*   __restrict__ gmask,    // (B,W,G)
    const int*   __restrict__ wvalid,   // (B,W)
    unsigned short* __restrict__ xb,    // (MPAD,H) bf16
    const float4* __restrict__ qw, const float4* __restrict__ ow,
    const float4* __restrict__ f1, const float4* __restrict__ f2,
    ushort4* __restrict__ dst)          // wb
{
    int bx = blockIdx.x;
    int tid = threadIdx.x;
    constexpr int NGATHER = (LW + 3) * B_;
    if (bx >= NGATHER) {
        // ---- weight fp32 -> bf16 ----
        constexpr int WL4 = WL_SZ / 4;
        int i = (bx - NGATHER) * 256 + tid;   // 0 .. 2*WL4
        int l = (i < WL4) ? 0 : 1;
        int j = i - l * WL4;
        float4 v;
        if (j < QW_SZ / 4)                          v = qw[l * (QW_SZ / 4) + j];
        else if (j < (QW_SZ + OW_SZ) / 4)           v = ow[l * (OW_SZ / 4) + j - QW_SZ / 4];
        else if (j < (QW_SZ + OW_SZ + F1_SZ) / 4)   v = f1[l * (F1_SZ / 4) + j - (QW_SZ + OW_SZ) / 4];
        else                                        v = f2[l * (F2_SZ / 4) + j - (QW_SZ + OW_SZ + F1_SZ) / 4];
        ushort4 o; o.x = f2b(v.x); o.y = f2b(v.y); o.z = f2b(v.z); o.w = f2b(v.w);
        dst[i] = o;
        return;
    }
    // ---- gather + masked mean pool -> xb (incl. pad-row zeroing) ----
    int t = bx % (LW + 3);
    int b = bx / (LW + 3);
    if (t >= LW) {
        int pr = M_ + b * 3 + (t - LW);
        size_t xo = (size_t)pr * H_;
#pragma unroll
        for (int i = 0; i < 3; i++) xb[xo + tid + i * 256] = 0;
        return;
    }
    size_t xo = ((size_t)b * LW + t) * H_;
    if (t == 0) {
        const float* src = hidden + (size_t)b * S_ * H_;   // token 0
#pragma unroll
        for (int i = 0; i < 3; i++) xb[xo + tid + i * 256] = f2b(src[tid + i * 256]);
    } else {
        int w = t - 1;
        int valid = wvalid[b * W_ + w];
        int ids[G_]; float msk[G_]; float cnt = 0.f;
#pragma unroll
        for (int g = 0; g < G_; g++) {
            ids[g] = wti[(b * W_ + w) * G_ + g];
            msk[g] = (gmask[(b * W_ + w) * G_ + g] != 0) ? 1.f : 0.f;
            cnt += msk[g];
        }
        float inv = valid ? (1.f / fmaxf(cnt, 1.f)) : 0.f;
#pragma unroll
        for (int i = 0; i < 3; i++) {
            int c = tid + i * 256;
            float a = 0.f;
#pragma unroll
            for (int g = 0; g < G_; g++)
                a += msk[g] * hidden[((size_t)b * S_ + ids[g]) * H_ + c];
            xb[xo + c] = f2b(a * inv);
        }
    }
}

// ---------------- LDS-staged bf16 MFMA GEMM body (shared by all GEMM kernels) ----------------
// XOR chunk swizzle (R6-verified). ldc: output leading dim. lda: A leading dim
// (CLS q-proj uses lda=LW*H to hit CLS rows). Pad rows read workspace junk; MFMA
// rows are row-local so junk stays in unread output rows.
template <int BM, int BN, int BK, int RELU, int OUTBF>
__device__ __forceinline__ void gemm_body(
    unsigned short* As, unsigned short* Bs,
    const unsigned short* __restrict__ A,   // (rows,lda) bf16
    const unsigned short* __restrict__ Bw,  // (N,K) bf16
    const float* __restrict__ bias,         // (N) f32
    void* __restrict__ Cout,                // (rows,ldc) f32 or bf16
    int N, int K, int ldc, int lda, int bm, int bn)
{
    constexpr int MI  = BM / 32;
    constexpr int NJ  = BN / 32;
    constexpr int CPR = BK / 8;
    constexpr int RPL = 2048 / BK;
    constexpr int SA  = BM * BK / 2048;
    constexpr int SB  = BN * BK / 2048;

    const int tid  = threadIdx.x;
    const int lane = tid & 63;
    const int wid  = tid >> 6;

    const int wm = (wid & 1) * (BM / 2);
    const int wn = (wid >> 1) * (BN / 2);
    const int r  = lane & 15;
    const int q8 = lane >> 4;
    const int m8 = r & (CPR - 1);

    const int srow = tid / CPR;
    const int scol = (tid % CPR) ^ (srow & (CPR - 1));
    const unsigned short* Ag = A  + (size_t)(bm + srow) * lda + scol * 8;
    const unsigned short* Bg = Bw + (size_t)(bn + srow) * K + scol * 8;

    const bf16_8* Af = (const bf16_8*)As;
    const bf16_8* Bf = (const bf16_8*)Bs;
    int arow[MI], brow[NJ];
#pragma unroll
    for (int i = 0; i < MI; i++) arow[i] = (wm + i * 16 + r) * CPR;
#pragma unroll
    for (int j = 0; j < NJ; j++) brow[j] = (wn + j * 16 + r) * CPR;

    f32x4 acc[MI][NJ];
#pragma unroll
    for (int i = 0; i < MI; i++)
#pragma unroll
        for (int j = 0; j < NJ; j++) acc[i][j] = (f32x4){0.f, 0.f, 0.f, 0.f};

    for (int k0 = 0; k0 < K; k0 += BK) {
#pragma unroll
        for (int s = 0; s < SA; s++)
            __builtin_amdgcn_global_load_lds(
                (const __attribute__((address_space(1))) void*)(Ag + (size_t)(s * RPL) * lda + k0),
                (__attribute__((address_space(3))) void*)(As + s * 2048 + tid * 8), 16, 0, 0);
#pragma unroll
        for (int s = 0; s < SB; s++)
            __builtin_amdgcn_global_load_lds(
                (const __attribute__((address_space(1))) void*)(Bg + (size_t)(s * RPL) * K + k0),
                (__attribute__((address_space(3))) void*)(Bs + s * 2048 + tid * 8), 16, 0, 0);
        __syncthreads();
#pragma unroll
        for (int ks = 0; ks < BK / 32; ks++) {
            const int cc = (ks * 4 + q8) ^ m8;
            bf16_8 a[MI], b[NJ];
#pragma unroll
            for (int i = 0; i < MI; i++) a[i] = Af[arow[i] + cc];
#pragma unroll
            for (int j = 0; j < NJ; j++) b[j] = Bf[brow[j] + cc];
#pragma unroll
            for (int i = 0; i < MI; i++)
#pragma unroll
                for (int j = 0; j < NJ; j++)
                    acc[i][j] = __builtin_amdgcn_mfma_f32_16x16x32_bf16(a[i], b[j], acc[i][j], 0, 0, 0);
        }
        __syncthreads();
    }

    int col[NJ]; float bv[NJ];
#pragma unroll
    for (int j = 0; j < NJ; j++) { col[j] = bn + wn + j * 16 + r; bv[j] = bias[col[j]]; }
    const int row0 = bm + wm + ((lane >> 4) << 2);
#pragma unroll
    for (int i = 0; i < MI; i++) {
#pragma unroll
        for (int rg = 0; rg < 4; rg++) {
            size_t rowoff = (size_t)(row0 + i * 16 + rg) * ldc;
#pragma unroll
            for (int j = 0; j < NJ; j++) {
                float v = acc[i][j][rg] + bv[j];
                if (RELU) v = fmaxf(v, 0.f);
                if (OUTBF) ((unsigned short*)Cout)[rowoff + col[j]] = f2b(v);
                else       ((float*)Cout)[rowoff + col[j]] = v;
            }
        }
    }
}

// ---------------- generic GEMM kernel (tiles = R0/R7-verified configs) ----------------
template <int BM, int BN, int BK, int RELU, int OUTBF, int SWZ>
__global__ __launch_bounds__(256) void gemm_mfma(
    const unsigned short* __restrict__ A,
    const unsigned short* __restrict__ Bw,
    const float* __restrict__ bias,
    void* __restrict__ Cout,
    int N, int K, int ldc, int lda)
{
    __shared__ __align__(16) unsigned short As[BM * BK];
    __shared__ __align__(16) unsigned short Bs[BN * BK];
    int bx = blockIdx.x, by = blockIdx.y;
    if (SWZ) {
        int nx = gridDim.x;
        int total = nx * gridDim.y;              // must be % 8 == 0
        int id = by * nx + bx;
        int id2 = (id & 7) * (total >> 3) + (id >> 3);
        by = id2 / nx; bx = id2 - by * nx;
    }
    gemm_body<BM, BN, BK, RELU, OUTBF>(As, Bs, A, Bw, bias, Cout, N, K, ldc, lda,
                                       by * BM, bx * BN);
}

// ---------------- R17: layer-1 KV GEMM + CLS q-proj in ONE launch ----------------
// grid (13,66): bx<12 = KV tiles (swizzled over 792), bx==12 & by<6 = q-proj tiles.
__global__ __launch_bounds__(256) void gemm_kv_q_kernel(
    const unsigned short* __restrict__ xb,
    const unsigned short* __restrict__ wkv,   // layer-1 qkv_w rows 768..2303 (K,V)
    const float* __restrict__ bkv,            // qkv_b + 3H + H
    unsigned short* __restrict__ kvout,       // qkvb + H (ldc = 3H)
    const unsigned short* __restrict__ wq,    // layer-1 qkv_w rows 0..767 (Q)
    const float* __restrict__ qb,             // qkv_b + 3H
    unsigned short* __restrict__ qrows)       // (64,H)
{
    __shared__ __align__(16) unsigned short As[64 * 64];
    __shared__ __align__(16) unsigned short Bs[128 * 64];
    int bx = blockIdx.x, by = blockIdx.y;
    if (bx == 12) {
        if (by >= 6) return;
        // q = CLS rows @ Wq^T + qb  (A strided by LW*H to hit CLS rows; bm=0)
        gemm_body<64, 128, 64, 0, 1>(As, Bs, xb, wq, qb, qrows,
                                     H_, H_, H_, LW * H_, 0, by * 128);
        return;
    }
    int id = by * 12 + bx;
    int id2 = (id & 7) * (792 >> 3) + (id >> 3);
    by = id2 / 12; bx = id2 - by * 12;
    gemm_body<64, 128, 64, 0, 1>(As, Bs, xb, wkv, bkv, kvout,
                                 2 * H_, H_, 3 * H_, H_, by * 64, bx * 128);
}

// ---------------- V transpose: qkvb V-third -> Vt[bh][192][KP] bf16 (zero-padded) ----------------
__global__ __launch_bounds__(256) void vt_kernel(
    const unsigned short* __restrict__ qkv,  // (MPAD, 3H)
    unsigned short* __restrict__ vtb)        // (128, HD_, KP)
{
    __shared__ __align__(16) unsigned short Vs[KR * KLD];
    int bh = blockIdx.x;
    int b = bh >> 2, h = bh & 3;
    int tid = threadIdx.x;
    for (int c = tid; c < KR * 24; c += 256) {
        int t = c / 24, j = c - t * 24;
        ushort8_t v = (ushort8_t){0,0,0,0,0,0,0,0};
        if (t < LW)
            v = *(const ushort8_t*)(qkv + (size_t)(b * LW + t) * (3 * H_) + 2 * H_ + h * HD_ + j * 8);
        *(ushort8_t*)(&Vs[t * KLD + j * 8]) = v;
    }
    __syncthreads();
    size_t obase = (size_t)bh * (HD_ * KP);
    for (int c = tid; c < HD_ * (KP / 4); c += 256) {
        int d = c / (KP / 4), t0 = (c - d * (KP / 4)) * 4;
        ushort4 o;
        o.x = (t0 + 0 < KR) ? Vs[(t0 + 0) * KLD + d] : 0;
        o.y = (t0 + 1 < KR) ? Vs[(t0 + 1) * KLD + d] : 0;
        o.z = (t0 + 2 < KR) ? Vs[(t0 + 2) * KLD + d] : 0;
        o.w = (t0 + 3 < KR) ? Vs[(t0 + 3) * KLD + d] : 0;
        *(ushort4*)(&vtb[obase + (size_t)d * KP + t0]) = o;
    }
}

// ---------------- fused scores+softmax+PV: P stays in LDS (layer-0 full attention) ----------------
// R17: mb==2 tile covers rows 128..191 but only row 128 is real — skip dead work.
__global__ __launch_bounds__(256) void attn_fused_kernel(
    const unsigned short* __restrict__ qkv,   // (MPAD, 3H)
    const int*            __restrict__ wvalid,
    const unsigned short* __restrict__ vtb,   // (128, HD_, KP)
    unsigned short*       __restrict__ ctx)   // (MPAD, H)
{
    __shared__ __align__(16) unsigned short Ks[KR * KLD];
    __shared__ __align__(16) unsigned short Ps[64 * PLD];
    __shared__ float msk[KR];
    int mb = blockIdx.x;          // 0..2
    int bh = blockIdx.y;
    int b = bh >> 2, h = bh & 3;
    int tid = threadIdx.x, lane = tid & 63, wid = tid >> 6;
    int q = lane >> 4, r = lane & 15;

    for (int c = tid; c < KR * 24; c += 256) {
        int t = c / 24, j = c - t * 24;
        ushort8_t v = (ushort8_t){0,0,0,0,0,0,0,0};
        if (t < LW)
            v = *(const ushort8_t*)(qkv + (size_t)(b * LW + t) * (3 * H_) + H_ + h * HD_ + j * 8);
        *(ushort8_t*)(&Ks[t * KLD + j * 8]) = v;
    }
    if (tid < KR) {
        bool valid = (tid == 0) || (tid <= W_ && wvalid[b * W_ + tid - 1] != 0);
        msk[tid] = valid ? 0.f : -1e30f;
    }
    __syncthreads();

    // ---- phase 1: scores + softmax, one 16-row tile per wave ----
    const int lrow0 = wid * 16;
    const bool p1_active = (mb < 2) || (lrow0 == 0);
    if (p1_active) {
        const unsigned short* Qp = qkv + ((size_t)(b * LW) + mb * 64 + lrow0 + r) * (3 * H_) + h * HD_;
        f32x4 acc[9];
#pragma unroll
        for (int nt = 0; nt < 9; nt++) acc[nt] = (f32x4){0.f, 0.f, 0.f, 0.f};
        for (int ks = 0; ks < HD_ / 32; ks++) {
            bf16_8 a = *(const bf16_8*)(Qp + ks * 32 + q * 8);
#pragma unroll
            for (int nt = 0; nt < 9; nt++) {
                bf16_8 bfrag = *(const bf16_8*)(&Ks[(nt * 16 + r) * KLD + ks * 32 + q * 8]);
                acc[nt] = __builtin_amdgcn_mfma_f32_16x16x32_bf16(a, bfrag, acc[nt], 0, 0, 0);
            }
        }
        float mk[9];
#pragma unroll
        for (int nt = 0; nt < 9; nt++) mk[nt] = msk[nt * 16 + r];
#pragma unroll
        for (int rg = 0; rg < 4; rg++) {
            float v[9]; float mx = -1e30f;
#pragma unroll
            for (int nt = 0; nt < 9; nt++) { v[nt] = acc[nt][rg] * SCALE_ + mk[nt]; mx = fmaxf(mx, v[nt]); }
#pragma unroll
            for (int off = 1; off < 16; off <<= 1) mx = fmaxf(mx, __shfl_xor(mx, off, 64));
            float s = 0.f;
#pragma unroll
            for (int nt = 0; nt < 9; nt++) { v[nt] = __expf(v[nt] - mx); s += v[nt]; }
#pragma unroll
            for (int off = 1; off < 16; off <<= 1) s += __shfl_xor(s, off, 64);
            float inv = 1.f / s;
            int lr = lrow0 + q * 4 + rg;
#pragma unroll
            for (int nt = 0; nt < 9; nt++)
                Ps[lr * PLD + nt * 16 + r] = f2b(v[nt] * inv);
            Ps[lr * PLD + KR + r] = 0;   // zero pad cols 144..159
        }
    }
    __syncthreads();

    // ---- phase 2: ctx = P @ V^T; waves 2m x 2n (32m x 96n each) ----
    const int wm = (wid & 1) * 32, wn = (wid >> 1) * 96;
    if (!(mb == 2 && wm == 32)) {
        size_t vbase = (size_t)bh * (HD_ * KP);
        f32x4 pacc[2][6];
#pragma unroll
        for (int i = 0; i < 2; i++)
#pragma unroll
            for (int j = 0; j < 6; j++) pacc[i][j] = (f32x4){0.f, 0.f, 0.f, 0.f};

        for (int ks = 0; ks < KP / 32; ks++) {
            bf16_8 a[2], bb[6];
#pragma unroll
            for (int i = 0; i < 2; i++)
                a[i] = *(const bf16_8*)(&Ps[(wm + i * 16 + r) * PLD + ks * 32 + q * 8]);
#pragma unroll
            for (int j = 0; j < 6; j++)
                bb[j] = *(const bf16_8*)(vtb + vbase + (size_t)(wn + j * 16 + r) * KP + ks * 32 + q * 8);
#pragma unroll
            for (int i = 0; i < 2; i++)
#pragma unroll
                for (int j = 0; j < 6; j++)
                    pacc[i][j] = __builtin_amdgcn_mfma_f32_16x16x32_bf16(a[i], bb[j], pacc[i][j], 0, 0, 0);
        }

#pragma unroll
        for (int i = 0; i < 2; i++) {
#pragma unroll
            for (int rg = 0; rg < 4; rg++) {
                int tl = mb * 64 + wm + i * 16 + q * 4 + rg;
                if (tl < LW) {
                    size_t rowoff = (size_t)(b * LW + tl) * H_ + h * HD_;
#pragma unroll
                    for (int j = 0; j < 6; j++)
                        ctx[rowoff + wn + j * 16 + r] = f2b(pacc[i][j][rg]);
                }
            }
        }
    }
}

// ---------------- fused residual add + LayerNorm (pure bf16 stream, f32 math) ----------------
__global__ __launch_bounds__(256) void add_ln_kernel(
    unsigned short* __restrict__ xb, const unsigned short* __restrict__ res,
    const float* __restrict__ sc, const float* __restrict__ bi)
{
    __shared__ float red[4];
    int row = blockIdx.x;
    int tid = threadIdx.x;
    size_t base = (size_t)row * H_;
    float v[3];
    float sum = 0.f;
#pragma unroll
    for (int i = 0; i < 3; i++) {
        int c = tid + i * 256;
        float t = b2f(xb[base + c]) + b2f(res[base + c]);
        v[i] = t; sum += t;
    }
    sum = block_sum(sum, red);
    float mean = sum * (1.f / H_);
    float var = 0.f;
#pragma unroll
    for (int i = 0; i < 3; i++) { float d = v[i] - mean; var += d * d; }
    var = block_sum(var, red);
    float inv = rsqrtf(var * (1.f / H_) + EPS_);
#pragma unroll
    for (int i = 0; i < 3; i++) {
        int c = tid + i * 256;
        xb[base + c] = f2b((v[i] - mean) * inv * sc[c] + bi[c]);
    }
}

// ---------------- R17: CLS attention core — coalesced K reads (8 lanes/key) ----------------
__global__ __launch_bounds__(256) void cls_attn_core2_kernel(
    const unsigned short* __restrict__ qrows,  // (64,H) bf16: rows 0..31 valid
    const unsigned short* __restrict__ qkvb,   // (MPAD,3H): cols 768..2303 = K,V (layer-1)
    const int* __restrict__ wvalid,
    unsigned short* __restrict__ ctxc)         // (64,H) bf16: rows 0..31 written
{
    __shared__ float qh[HD_];
    __shared__ float sr[160];
    __shared__ float ps[LW];
    __shared__ float red[4];
    int b = blockIdx.x, h = blockIdx.y;
    int tid = threadIdx.x, lane = tid & 63, wid = tid >> 6;
    if (tid < HD_) qh[tid] = b2f(qrows[(size_t)b * H_ + h * HD_ + tid]);
    __syncthreads();
    // scores: 8 lanes per key — each lane reads a contiguous 48B chunk of the 384B K-row
    int grp = tid >> 3, s8 = tid & 7;
#pragma unroll
    for (int p = 0; p < 5; p++) {
        int t = p * 32 + grp;
        float acc = 0.f;
        if (t < LW) {
            const unsigned short* kr = qkvb + (size_t)(b * LW + t) * (3 * H_) + H_ + h * HD_ + s8 * 24;
#pragma unroll
            for (int j = 0; j < 3; j++) {
                ushort8_t k8 = *(const ushort8_t*)(kr + j * 8);
#pragma unroll
                for (int jj = 0; jj < 8; jj++) acc += qh[s8 * 24 + j * 8 + jj] * b2f(k8[jj]);
            }
        }
        acc += __shfl_xor(acc, 1, 64);
        acc += __shfl_xor(acc, 2, 64);
        acc += __shfl_xor(acc, 4, 64);
        if (s8 == 0 && t < LW) {
            bool valid = (t == 0) || (wvalid[b * W_ + t - 1] != 0);
            sr[t] = valid ? acc * SCALE_ : -1e30f;
        }
    }
    __syncthreads();
    // block-wide softmax over 129
    float sc = (tid < LW) ? sr[tid] : -1e30f;
    float mx = wave_max(sc);
    if (lane == 0) red[wid] = mx;
    __syncthreads();
    mx = fmaxf(fmaxf(red[0], red[1]), fmaxf(red[2], red[3]));
    __syncthreads();
    float e = (tid < LW) ? __expf(sc - mx) : 0.f;
    float ssum = wave_sum(e);
    if (lane == 0) red[wid] = ssum;
    __syncthreads();
    ssum = (red[0] + red[1]) + (red[2] + red[3]);
    if (tid < LW) ps[tid] = e * (1.f / ssum);
    __syncthreads();
    // ctx: thread d; V reads coalesced across the wave (consecutive d per row)
    if (tid < HD_) {
        const unsigned short* vb = qkvb + (size_t)(b * LW) * (3 * H_) + 2 * H_ + h * HD_ + tid;
        float cx = 0.f;
#pragma unroll 8
        for (int t = 0; t < LW; t++)
            cx += ps[t] * b2f(vb[(size_t)t * (3 * H_)]);
        ctxc[(size_t)b * H_ + h * HD_ + tid] = f2b(cx);
    }
}

// ---------------- R15: out-proj result + CLS residual (from xb) + LN1 -> xc64 ----------------
__global__ __launch_bounds__(256) void cls_ln1_kernel(
    const unsigned short* __restrict__ proj,  // (64,H): out-proj output (incl bias)
    const unsigned short* __restrict__ xb,    // (MPAD,H): residual = CLS rows
    const float* __restrict__ sc, const float* __restrict__ bi,
    unsigned short* __restrict__ dst)         // (64,H): rows 0..31 written
{
    __shared__ float red[4];
    int b = blockIdx.x;
    int tid = threadIdx.x;
    float v[3]; float sum = 0.f;
#pragma unroll
    for (int i = 0; i < 3; i++) {
        int c = tid + i * 256;
        float t = b2f(proj[(size_t)b * H_ + c]) + b2f(xb[(size_t)(b * LW) * H_ + c]);
        v[i] = t; sum += t;
    }
    sum = block_sum(sum, red);
    float mean = sum * (1.f / H_);
    float var = 0.f;
#pragma unroll
    for (int i = 0; i < 3; i++) { float d = v[i] - mean; var += d * d; }
    var = block_sum(var, red);
    float inv = rsqrtf(var * (1.f / H_) + EPS_);
#pragma unroll
    for (int i = 0; i < 3; i++) {
        int c = tid + i * 256;
        dst[(size_t)b * H_ + c] = f2b((v[i] - mean) * inv * sc[c] + bi[c]);
    }
}

// ---------------- R14: final residual + LN2 + pooled + logits (32 rows) ----------------
__global__ __launch_bounds__(256) void cls_final_kernel(
    const unsigned short* __restrict__ proj,  // (64,H): ff2 output (incl bias)
    const unsigned short* __restrict__ resid, // (64,H): xc64
    const float* __restrict__ ln2s, const float* __restrict__ ln2b,
    const float* __restrict__ cls_w, const float* __restrict__ cls_b,
    float* __restrict__ out)
{
    __shared__ float red[4];
    __shared__ float lred[4][NLAB_];
    int b = blockIdx.x;
    int tid = threadIdx.x, lane = tid & 63, wid = tid >> 6;
    size_t base = (size_t)b * H_;
    float v[3]; float sum = 0.f;
#pragma unroll
    for (int i = 0; i < 3; i++) {
        int c = tid + i * 256;
        float t = b2f(proj[base + c]) + b2f(resid[base + c]);
        v[i] = t; sum += t;
    }
    sum = block_sum(sum, red);
    float mean = sum * (1.f / H_);
    float var = 0.f;
#pragma unroll
    for (int i = 0; i < 3; i++) { float d = v[i] - mean; var += d * d; }
    var = block_sum(var, red);
    float rinv = rsqrtf(var * (1.f / H_) + EPS_);
    float f3[3];
#pragma unroll
    for (int i = 0; i < 3; i++) {
        int c = tid + i * 256;
        f3[i] = (v[i] - mean) * rinv * ln2s[c] + ln2b[c];
        out[B_ * NLAB_ + b * H_ + c] = f3[i];
    }
    float l6[NLAB_] = {0.f, 0.f, 0.f, 0.f, 0.f, 0.f};
#pragma unroll
    for (int i = 0; i < 3; i++) {
        int c = tid + i * 256;
#pragma unroll
        for (int w = 0; w < NLAB_; w++) l6[w] += f3[i] * cls_w[w * H_ + c];
    }
#pragma unroll
    for (int w = 0; w < NLAB_; w++) l6[w] = wave_sum(l6[w]);
    if (lane == 0) {
#pragma unroll
        for (int w = 0; w < NLAB_; w++) lred[wid][w] = l6[w];
    }
    __syncthreads();
    if (tid < NLAB_)
        out[b * NLAB_ + tid] = lred[0][tid] + lred[1][tid] + lred[2][tid] + lred[3][tid] + cls_b[tid];
}

extern "C" void kernel_launch(void* const* d_in, const int* in_sizes, int n_in,
                              void* d_out, int out_size, void* d_ws, size_t ws_size,
                              hipStream_t stream) {
    const float* hidden = (const float*)d_in[0];
    const int*   wti    = (const int*)d_in[1];
    const int*   gmask  = (const int*)d_in[2];
    const int*   wvalid = (const int*)d_in[3];
    const float* qkv_w  = (const float*)d_in[4];
    const float* qkv_b  = (const float*)d_in[5];
    const float* out_w  = (const float*)d_in[6];
    const float* out_b  = (const float*)d_in[7];
    const float* ff1_w  = (const float*)d_in[8];
    const float* ff1_b  = (const float*)d_in[9];
    const float* ff2_w  = (const float*)d_in[10];
    const float* ff2_b  = (const float*)d_in[11];
    const float* ln1_s  = (const float*)d_in[12];
    const float* ln1_b  = (const float*)d_in[13];
    const float* ln2_s  = (const float*)d_in[14];
    const float* ln2_b  = (const float*)d_in[15];
    const float* cls_w  = (const float*)d_in[16];
    const float* cls_b  = (const float*)d_in[17];
    float* out = (float*)d_out;

    // workspace (all bf16): ~62 MB
    const size_t XSZ = (size_t)MPAD * H_;             // 3,244,032
    const size_t ASZ = (size_t)128 * TP * KP;         // 3,932,160
    const size_t R64 = (size_t)64 * H_;               // 49,152
    unsigned short* U    = (unsigned short*)d_ws;     // ASZ region: vtb/tmpb layer 0; CLS bufs layer 1
    unsigned short* vtb  = U;
    unsigned short* tmpb = U;                         // lifetimes disjoint
    unsigned short* qrows64 = U + 1 * R64;            // (64,H) q projections (rows 32..63 junk)
    unsigned short* ctxc  = U + 2 * R64;              // (64,H) attention context (rows 32..63 junk)
    unsigned short* xc64  = U + 3 * R64;              // (64,H) after LN1 (rows 32..63 junk)
    unsigned short* tmp64 = U + 4 * R64;              // (64,H) proj scratch
    unsigned short* h1c   = U + 5 * R64;              // (64,FF)
    unsigned short* xb   = U + ASZ;                   // XSZ
    unsigned short* ctxb = xb + XSZ;                  // XSZ
    unsigned short* qkvb = ctxb + XSZ;                // 3*XSZ (aliased: h1 MPAD*FF)
    unsigned short* wb   = qkvb + (size_t)MPAD * 3 * H_;     // 2*WL_SZ (both layers)

    // fused gather+pool + weight conversion (one launch)
    build_cvt_kernel<<<(LW + 3) * B_ + 2 * WL_SZ / 4 / 256, 256, 0, stream>>>(
        hidden, wti, gmask, wvalid, xb,
        (const float4*)qkv_w, (const float4*)out_w,
        (const float4*)ff1_w, (const float4*)ff2_w, (ushort4*)wb);

    const int GM = MPAD / 64;   // 66 m-blocks

    // ---------------- layer 0: full transformer block (R0/R7-verified configs) ----------------
    {
        unsigned short* wbl = wb;
        gemm_mfma<64, 128, 64, 0, 1, 0><<<dim3(3 * H_ / 128, GM), 256, 0, stream>>>(
            xb, wbl, qkv_b, qkvb, 3 * H_, H_, 3 * H_, H_);
        vt_kernel<<<128, 256, 0, stream>>>(qkvb, vtb);
        attn_fused_kernel<<<dim3(3, 128), 256, 0, stream>>>(qkvb, wvalid, vtb, ctxb);
        gemm_mfma<64, 64, 64, 0, 1, 1><<<dim3(H_ / 64, GM), 256, 0, stream>>>(
            ctxb, wbl + QW_SZ, out_b, tmpb, H_, H_, H_, H_);
        add_ln_kernel<<<M_, 256, 0, stream>>>(xb, tmpb, ln1_s, ln1_b);
        gemm_mfma<64, 128, 64, 1, 1, 1><<<dim3(FF_ / 128, GM), 256, 0, stream>>>(
            xb, wbl + QW_SZ + OW_SZ, ff1_b, qkvb, FF_, H_, FF_, H_);
        gemm_mfma<64, 64, 64, 0, 1, 1><<<dim3(H_ / 64, GM), 256, 0, stream>>>(
            qkvb, wbl + QW_SZ + OW_SZ + F1_SZ, ff2_b, tmpb, H_, FF_, H_, FF_);
        add_ln_kernel<<<M_, 256, 0, stream>>>(xb, tmpb, ln2_s, ln2_b);
    }

    // ---------------- layer 1: CLS-only path (only x[:,0,:] is read downstream) ----------------
    {
        unsigned short* wbl = wb + WL_SZ;
        // K,V for all rows + CLS q-proj, one launch (grid 13x66)
        gemm_kv_q_kernel<<<dim3(13, GM), 256, 0, stream>>>(
            xb, wbl + (size_t)H_ * H_, qkv_b + 3 * H_ + H_, qkvb + H_,
            wbl, qkv_b + 3 * H_, qrows64);
        // attention core (128 blocks: one per (b,h))
        cls_attn_core2_kernel<<<dim3(B_, NH_), 256, 0, stream>>>(
            qrows64, qkvb, wvalid, ctxc);
        // out-proj (R20: 64x64 tiles, 12 blocks — halve serial K-loop latency)
        gemm_mfma<64, 64, 64, 0, 1, 0><<<dim3(H_ / 64, 1), 256, 0, stream>>>(
            ctxc, wbl + QW_SZ, out_b + H_, tmp64, H_, H_, H_, H_);
        // LN1 (residual read directly from xb CLS rows) -> xc64
        cls_ln1_kernel<<<B_, 256, 0, stream>>>(tmp64, xb, ln1_s + H_, ln1_b + H_, xc64);
        // ff1 + relu (R20: 64x64 tiles, 32 blocks)
        gemm_mfma<64, 64, 64, 1, 1, 0><<<dim3(FF_ / 64, 1), 256, 0, stream>>>(
            xc64, wbl + QW_SZ + OW_SZ, ff1_b + FF_, h1c, FF_, H_, FF_, H_);
        // ff2 (R20: 64x64 tiles, 12 blocks)
        gemm_mfma<64, 64, 64, 0, 1, 0><<<dim3(H_ / 64, 1), 256, 0, stream>>>(
            h1c, wbl + QW_SZ + OW_SZ + F1_SZ, ff2_b + H_, tmp64, H_, FF_, H_, FF_);
        // LN2 + pooled + logits
        cls_final_kernel<<<B_, 256, 0, stream>>>(tmp64, xc64, ln2_s + H_, ln2_b + H_,
                                                 cls_w, cls_b, out);
    }
    (void)in_sizes; (void)n_in; (void)out_size; (void)ws_size;
}

// Round 12
// 367.991 us; speedup vs baseline: 1.2997x; 1.0064x over previous
//
#include <hip/hip_runtime.h>
#include <hip/hip_bf16.h>
#include <math.h>

// Problem constants
#define B_  32
#define S_  512
#define H_  768
#define W_  128
#define G_  4
#define LW  129          // W+1
#define NH_ 4
#define HD_ 192
#define FF_ 2048
#define NL_ 2
#define NLAB_ 6
#define M_   (B_ * LW)   // 4128 rows of x
#define MPAD 4224        // 33 * 128 — zero GEMM bounds checks
#define EPS_ 1e-5f
#define SCALE_ 0.07216878364870323f   // 1/sqrt(192)

// attention padded dims (layer-0 full attention)
#define TP 192           // padded query rows per (b,h)
#define KP 160           // padded key count (mult of 32)
#define KR 144           // staged key rows (9 n-tiles)
#define KLD 200          // LDS row stride for K stage (bank-friendly)
#define PLD 168          // LDS row stride for P (bank-friendly for b128 frag reads)

#define QW_SZ (3 * H_ * H_)   // 1769472
#define OW_SZ (H_ * H_)       // 589824
#define F1_SZ (FF_ * H_)      // 1572864
#define F2_SZ (H_ * FF_)      // 1572864
#define WL_SZ (QW_SZ + OW_SZ + F1_SZ + F2_SZ)  // 5505024

typedef __bf16 bf16_8 __attribute__((ext_vector_type(8)));
typedef float  f32x4  __attribute__((ext_vector_type(4)));
typedef unsigned short ushort8_t __attribute__((ext_vector_type(8)));

__device__ __forceinline__ float b2f(unsigned short u) {
    union { unsigned int i; float f; } c; c.i = ((unsigned int)u) << 16; return c.f;
}
__device__ __forceinline__ unsigned short f2b(float f) {
    union { float f; unsigned int u; } c; c.f = f;
    unsigned int u = c.u;
    return (unsigned short)((u + 0x7FFFu + ((u >> 16) & 1u)) >> 16);   // RNE
}

// ---------------- reductions ----------------
__device__ __forceinline__ float wave_sum(float v) {
#pragma unroll
    for (int off = 1; off < 64; off <<= 1) v += __shfl_xor(v, off, 64);
    return v;
}
__device__ __forceinline__ float wave_max(float v) {
#pragma unroll
    for (int off = 1; off < 64; off <<= 1) v = fmaxf(v, __shfl_xor(v, off, 64));
    return v;
}
__device__ __forceinline__ float block_sum(float v, float* red) {
    v = wave_sum(v);
    int wid = threadIdx.x >> 6, lane = threadIdx.x & 63;
    if (lane == 0) red[wid] = v;
    __syncthreads();
    float r = (red[0] + red[1]) + (red[2] + red[3]);
    __syncthreads();
    return r;
}

// ---------------- R15: fused gather+pool AND weight cvt (one launch, both BW-bound) ----------------
__global__ __launch_bounds__(256) void build_cvt_kernel(
    const float* __restrict__ hidden,   // (B,S,H)
    const int*   __restrict__ wti,      // (B,W,G)
    const int*   __restrict__ gmask,    // (B,W,G)
    const int*   __restrict__ wvalid,   // (B,W)
    unsigned short* __restrict__ xb,    // (MPAD,H) bf16
    const float4* __restrict__ qw, const float4* __restrict__ ow,
    const float4* __restrict__ f1, const float4* __restrict__ f2,
    ushort4* __restrict__ dst)          // wb
{
    int bx = blockIdx.x;
    int tid = threadIdx.x;
    constexpr int NGATHER = (LW + 3) * B_;
    if (bx >= NGATHER) {
        // ---- weight fp32 -> bf16 ----
        constexpr int WL4 = WL_SZ / 4;
        int i = (bx - NGATHER) * 256 + tid;   // 0 .. 2*WL4
        int l = (i < WL4) ? 0 : 1;
        int j = i - l * WL4;
        float4 v;
        if (j < QW_SZ / 4)                          v = qw[l * (QW_SZ / 4) + j];
        else if (j < (QW_SZ + OW_SZ) / 4)           v = ow[l * (OW_SZ / 4) + j - QW_SZ / 4];
        else if (j < (QW_SZ + OW_SZ + F1_SZ) / 4)   v = f1[l * (F1_SZ / 4) + j - (QW_SZ + OW_SZ) / 4];
        else                                        v = f2[l * (F2_SZ / 4) + j - (QW_SZ + OW_SZ + F1_SZ) / 4];
        ushort4 o; o.x = f2b(v.x); o.y = f2b(v.y); o.z = f2b(v.z); o.w = f2b(v.w);
        dst[i] = o;
        return;
    }
    // ---- gather + masked mean pool -> xb (incl. pad-row zeroing) ----
    int t = bx % (LW + 3);
    int b = bx / (LW + 3);
    if (t >= LW) {
        int pr = M_ + b * 3 + (t - LW);
        size_t xo = (size_t)pr * H_;
#pragma unroll
        for (int i = 0; i < 3; i++) xb[xo + tid + i * 256] = 0;
        return;
    }
    size_t xo = ((size_t)b * LW + t) * H_;
    if (t == 0) {
        const float* src = hidden + (size_t)b * S_ * H_;   // token 0
#pragma unroll
        for (int i = 0; i < 3; i++) xb[xo + tid + i * 256] = f2b(src[tid + i * 256]);
    } else {
        int w = t - 1;
        int valid = wvalid[b * W_ + w];
        int ids[G_]; float msk[G_]; float cnt = 0.f;
#pragma unroll
        for (int g = 0; g < G_; g++) {
            ids[g] = wti[(b * W_ + w) * G_ + g];
            msk[g] = (gmask[(b * W_ + w) * G_ + g] != 0) ? 1.f : 0.f;
            cnt += msk[g];
        }
        float inv = valid ? (1.f / fmaxf(cnt, 1.f)) : 0.f;
#pragma unroll
        for (int i = 0; i < 3; i++) {
            int c = tid + i * 256;
            float a = 0.f;
#pragma unroll
            for (int g = 0; g < G_; g++)
                a += msk[g] * hidden[((size_t)b * S_ + ids[g]) * H_ + c];
            xb[xo + c] = f2b(a * inv);
        }
    }
}

// ---------------- LDS-staged bf16 MFMA GEMM body (shared by all GEMM kernels) ----------------
// XOR chunk swizzle (R6-verified). ldc: output leading dim. lda: A leading dim
// (CLS q-proj uses lda=LW*H to hit CLS rows). Pad rows read workspace junk; MFMA
// rows are row-local so junk stays in unread output rows.
template <int BM, int BN, int BK, int RELU, int OUTBF>
__device__ __forceinline__ void gemm_body(
    unsigned short* As, unsigned short* Bs,
    const unsigned short* __restrict__ A,   // (rows,lda) bf16
    const unsigned short* __restrict__ Bw,  // (N,K) bf16
    const float* __restrict__ bias,         // (N) f32
    void* __restrict__ Cout,                // (rows,ldc) f32 or bf16
    int N, int K, int ldc, int lda, int bm, int bn)
{
    constexpr int MI  = BM / 32;
    constexpr int NJ  = BN / 32;
    constexpr int CPR = BK / 8;
    constexpr int RPL = 2048 / BK;
    constexpr int SA  = BM * BK / 2048;
    constexpr int SB  = BN * BK / 2048;

    const int tid  = threadIdx.x;
    const int lane = tid & 63;
    const int wid  = tid >> 6;

    const int wm = (wid & 1) * (BM / 2);
    const int wn = (wid >> 1) * (BN / 2);
    const int r  = lane & 15;
    const int q8 = lane >> 4;
    const int m8 = r & (CPR - 1);

    const int srow = tid / CPR;
    const int scol = (tid % CPR) ^ (srow & (CPR - 1));
    const unsigned short* Ag = A  + (size_t)(bm + srow) * lda + scol * 8;
    const unsigned short* Bg = Bw + (size_t)(bn + srow) * K + scol * 8;

    const bf16_8* Af = (const bf16_8*)As;
    const bf16_8* Bf = (const bf16_8*)Bs;
    int arow[MI], brow[NJ];
#pragma unroll
    for (int i = 0; i < MI; i++) arow[i] = (wm + i * 16 + r) * CPR;
#pragma unroll
    for (int j = 0; j < NJ; j++) brow[j] = (wn + j * 16 + r) * CPR;

    f32x4 acc[MI][NJ];
#pragma unroll
    for (int i = 0; i < MI; i++)
#pragma unroll
        for (int j = 0; j < NJ; j++) acc[i][j] = (f32x4){0.f, 0.f, 0.f, 0.f};

    for (int k0 = 0; k0 < K; k0 += BK) {
#pragma unroll
        for (int s = 0; s < SA; s++)
            __builtin_amdgcn_global_load_lds(
                (const __attribute__((address_space(1))) void*)(Ag + (size_t)(s * RPL) * lda + k0),
                (__attribute__((address_space(3))) void*)(As + s * 2048 + tid * 8), 16, 0, 0);
#pragma unroll
        for (int s = 0; s < SB; s++)
            __builtin_amdgcn_global_load_lds(
                (const __attribute__((address_space(1))) void*)(Bg + (size_t)(s * RPL) * K + k0),
                (__attribute__((address_space(3))) void*)(Bs + s * 2048 + tid * 8), 16, 0, 0);
        __syncthreads();
#pragma unroll
        for (int ks = 0; ks < BK / 32; ks++) {
            const int cc = (ks * 4 + q8) ^ m8;
            bf16_8 a[MI], b[NJ];
#pragma unroll
            for (int i = 0; i < MI; i++) a[i] = Af[arow[i] + cc];
#pragma unroll
            for (int j = 0; j < NJ; j++) b[j] = Bf[brow[j] + cc];
#pragma unroll
            for (int i = 0; i < MI; i++)
#pragma unroll
                for (int j = 0; j < NJ; j++)
                    acc[i][j] = __builtin_amdgcn_mfma_f32_16x16x32_bf16(a[i], b[j], acc[i][j], 0, 0, 0);
        }
        __syncthreads();
    }

    int col[NJ]; float bv[NJ];
#pragma unroll
    for (int j = 0; j < NJ; j++) { col[j] = bn + wn + j * 16 + r; bv[j] = bias[col[j]]; }
    const int row0 = bm + wm + ((lane >> 4) << 2);
#pragma unroll
    for (int i = 0; i < MI; i++) {
#pragma unroll
        for (int rg = 0; rg < 4; rg++) {
            size_t rowoff = (size_t)(row0 + i * 16 + rg) * ldc;
#pragma unroll
            for (int j = 0; j < NJ; j++) {
                float v = acc[i][j][rg] + bv[j];
                if (RELU) v = fmaxf(v, 0.f);
                if (OUTBF) ((unsigned short*)Cout)[rowoff + col[j]] = f2b(v);
                else       ((float*)Cout)[rowoff + col[j]] = v;
            }
        }
    }
}

// ---------------- generic GEMM kernel ----------------
// SWZ=0: none | SWZ=1: %8 grids (R6-verified) | SWZ=2 (R21): bijective m204-style
// band remap for non-%8 grids (qkv: 1188 blocks -> q=148,r=4).
template <int BM, int BN, int BK, int RELU, int OUTBF, int SWZ>
__global__ __launch_bounds__(256) void gemm_mfma(
    const unsigned short* __restrict__ A,
    const unsigned short* __restrict__ Bw,
    const float* __restrict__ bias,
    void* __restrict__ Cout,
    int N, int K, int ldc, int lda)
{
    __shared__ __align__(16) unsigned short As[BM * BK];
    __shared__ __align__(16) unsigned short Bs[BN * BK];
    int bx = blockIdx.x, by = blockIdx.y;
    if (SWZ == 1) {
        int nx = gridDim.x;
        int total = nx * gridDim.y;              // must be % 8 == 0
        int id = by * nx + bx;
        int id2 = (id & 7) * (total >> 3) + (id >> 3);
        by = id2 / nx; bx = id2 - by * nx;
    } else if (SWZ == 2) {
        int nx = gridDim.x;
        int total = nx * gridDim.y;              // any size (bijective banding)
        int id = by * nx + bx;
        int qq = total >> 3, rr = total & 7;
        int xcd = id & 7, idx = id >> 3;
        int id2 = (xcd < rr) ? xcd * (qq + 1) + idx
                             : rr * (qq + 1) + (xcd - rr) * qq + idx;
        by = id2 / nx; bx = id2 - by * nx;
    }
    gemm_body<BM, BN, BK, RELU, OUTBF>(As, Bs, A, Bw, bias, Cout, N, K, ldc, lda,
                                       by * BM, bx * BN);
}

// ---------------- R17: layer-1 KV GEMM + CLS q-proj in ONE launch ----------------
// grid (13,66): bx<12 = KV tiles (swizzled over 792), bx==12 & by<6 = q-proj tiles.
__global__ __launch_bounds__(256) void gemm_kv_q_kernel(
    const unsigned short* __restrict__ xb,
    const unsigned short* __restrict__ wkv,   // layer-1 qkv_w rows 768..2303 (K,V)
    const float* __restrict__ bkv,            // qkv_b + 3H + H
    unsigned short* __restrict__ kvout,       // qkvb + H (ldc = 3H)
    const unsigned short* __restrict__ wq,    // layer-1 qkv_w rows 0..767 (Q)
    const float* __restrict__ qb,             // qkv_b + 3H
    unsigned short* __restrict__ qrows)       // (64,H)
{
    __shared__ __align__(16) unsigned short As[64 * 64];
    __shared__ __align__(16) unsigned short Bs[128 * 64];
    int bx = blockIdx.x, by = blockIdx.y;
    if (bx == 12) {
        if (by >= 6) return;
        // q = CLS rows @ Wq^T + qb  (A strided by LW*H to hit CLS rows; bm=0)
        gemm_body<64, 128, 64, 0, 1>(As, Bs, xb, wq, qb, qrows,
                                     H_, H_, H_, LW * H_, 0, by * 128);
        return;
    }
    int id = by * 12 + bx;
    int id2 = (id & 7) * (792 >> 3) + (id >> 3);
    by = id2 / 12; bx = id2 - by * 12;
    gemm_body<64, 128, 64, 0, 1>(As, Bs, xb, wkv, bkv, kvout,
                                 2 * H_, H_, 3 * H_, H_, by * 64, bx * 128);
}

// ---------------- V transpose: qkvb V-third -> Vt[bh][192][KP] bf16 (zero-padded) ----------------
__global__ __launch_bounds__(256) void vt_kernel(
    const unsigned short* __restrict__ qkv,  // (MPAD, 3H)
    unsigned short* __restrict__ vtb)        // (128, HD_, KP)
{
    __shared__ __align__(16) unsigned short Vs[KR * KLD];
    int bh = blockIdx.x;
    int b = bh >> 2, h = bh & 3;
    int tid = threadIdx.x;
    for (int c = tid; c < KR * 24; c += 256) {
        int t = c / 24, j = c - t * 24;
        ushort8_t v = (ushort8_t){0,0,0,0,0,0,0,0};
        if (t < LW)
            v = *(const ushort8_t*)(qkv + (size_t)(b * LW + t) * (3 * H_) + 2 * H_ + h * HD_ + j * 8);
        *(ushort8_t*)(&Vs[t * KLD + j * 8]) = v;
    }
    __syncthreads();
    size_t obase = (size_t)bh * (HD_ * KP);
    for (int c = tid; c < HD_ * (KP / 4); c += 256) {
        int d = c / (KP / 4), t0 = (c - d * (KP / 4)) * 4;
        ushort4 o;
        o.x = (t0 + 0 < KR) ? Vs[(t0 + 0) * KLD + d] : 0;
        o.y = (t0 + 1 < KR) ? Vs[(t0 + 1) * KLD + d] : 0;
        o.z = (t0 + 2 < KR) ? Vs[(t0 + 2) * KLD + d] : 0;
        o.w = (t0 + 3 < KR) ? Vs[(t0 + 3) * KLD + d] : 0;
        *(ushort4*)(&vtb[obase + (size_t)d * KP + t0]) = o;
    }
}

// ---------------- fused scores+softmax+PV: P stays in LDS (layer-0 full attention) ----------------
// R17: mb==2 tile covers rows 128..191 but only row 128 is real — skip dead work.
// R21: mb==2 wm==0 waves also skip the i=1 sub-tile (rows 144..159, all dead).
__global__ __launch_bounds__(256) void attn_fused_kernel(
    const unsigned short* __restrict__ qkv,   // (MPAD, 3H)
    const int*            __restrict__ wvalid,
    const unsigned short* __restrict__ vtb,   // (128, HD_, KP)
    unsigned short*       __restrict__ ctx)   // (MPAD, H)
{
    __shared__ __align__(16) unsigned short Ks[KR * KLD];
    __shared__ __align__(16) unsigned short Ps[64 * PLD];
    __shared__ float msk[KR];
    int mb = blockIdx.x;          // 0..2
    int bh = blockIdx.y;
    int b = bh >> 2, h = bh & 3;
    int tid = threadIdx.x, lane = tid & 63, wid = tid >> 6;
    int q = lane >> 4, r = lane & 15;

    for (int c = tid; c < KR * 24; c += 256) {
        int t = c / 24, j = c - t * 24;
        ushort8_t v = (ushort8_t){0,0,0,0,0,0,0,0};
        if (t < LW)
            v = *(const ushort8_t*)(qkv + (size_t)(b * LW + t) * (3 * H_) + H_ + h * HD_ + j * 8);
        *(ushort8_t*)(&Ks[t * KLD + j * 8]) = v;
    }
    if (tid < KR) {
        bool valid = (tid == 0) || (tid <= W_ && wvalid[b * W_ + tid - 1] != 0);
        msk[tid] = valid ? 0.f : -1e30f;
    }
    __syncthreads();

    // ---- phase 1: scores + softmax, one 16-row tile per wave ----
    const int lrow0 = wid * 16;
    const bool p1_active = (mb < 2) || (lrow0 == 0);
    if (p1_active) {
        const unsigned short* Qp = qkv + ((size_t)(b * LW) + mb * 64 + lrow0 + r) * (3 * H_) + h * HD_;
        f32x4 acc[9];
#pragma unroll
        for (int nt = 0; nt < 9; nt++) acc[nt] = (f32x4){0.f, 0.f, 0.f, 0.f};
        for (int ks = 0; ks < HD_ / 32; ks++) {
            bf16_8 a = *(const bf16_8*)(Qp + ks * 32 + q * 8);
#pragma unroll
            for (int nt = 0; nt < 9; nt++) {
                bf16_8 bfrag = *(const bf16_8*)(&Ks[(nt * 16 + r) * KLD + ks * 32 + q * 8]);
                acc[nt] = __builtin_amdgcn_mfma_f32_16x16x32_bf16(a, bfrag, acc[nt], 0, 0, 0);
            }
        }
        float mk[9];
#pragma unroll
        for (int nt = 0; nt < 9; nt++) mk[nt] = msk[nt * 16 + r];
#pragma unroll
        for (int rg = 0; rg < 4; rg++) {
            float v[9]; float mx = -1e30f;
#pragma unroll
            for (int nt = 0; nt < 9; nt++) { v[nt] = acc[nt][rg] * SCALE_ + mk[nt]; mx = fmaxf(mx, v[nt]); }
#pragma unroll
            for (int off = 1; off < 16; off <<= 1) mx = fmaxf(mx, __shfl_xor(mx, off, 64));
            float s = 0.f;
#pragma unroll
            for (int nt = 0; nt < 9; nt++) { v[nt] = __expf(v[nt] - mx); s += v[nt]; }
#pragma unroll
            for (int off = 1; off < 16; off <<= 1) s += __shfl_xor(s, off, 64);
            float inv = 1.f / s;
            int lr = lrow0 + q * 4 + rg;
#pragma unroll
            for (int nt = 0; nt < 9; nt++)
                Ps[lr * PLD + nt * 16 + r] = f2b(v[nt] * inv);
            Ps[lr * PLD + KR + r] = 0;   // zero pad cols 144..159
        }
    }
    __syncthreads();

    // ---- phase 2: ctx = P @ V^T; waves 2m x 2n (32m x 96n each) ----
    const int wm = (wid & 1) * 32, wn = (wid >> 1) * 96;
    if (!(mb == 2 && wm == 32)) {
        const int mi = (mb == 2) ? 1 : 2;   // R21: mb2 keeps only rows 128..143
        size_t vbase = (size_t)bh * (HD_ * KP);
        f32x4 pacc[2][6];
#pragma unroll
        for (int i = 0; i < 2; i++)
#pragma unroll
            for (int j = 0; j < 6; j++) pacc[i][j] = (f32x4){0.f, 0.f, 0.f, 0.f};

        for (int ks = 0; ks < KP / 32; ks++) {
            bf16_8 a[2], bb[6];
#pragma unroll
            for (int i = 0; i < 2; i++)
                if (i < mi)
                    a[i] = *(const bf16_8*)(&Ps[(wm + i * 16 + r) * PLD + ks * 32 + q * 8]);
#pragma unroll
            for (int j = 0; j < 6; j++)
                bb[j] = *(const bf16_8*)(vtb + vbase + (size_t)(wn + j * 16 + r) * KP + ks * 32 + q * 8);
#pragma unroll
            for (int i = 0; i < 2; i++)
                if (i < mi)
#pragma unroll
                    for (int j = 0; j < 6; j++)
                        pacc[i][j] = __builtin_amdgcn_mfma_f32_16x16x32_bf16(a[i], bb[j], pacc[i][j], 0, 0, 0);
        }

#pragma unroll
        for (int i = 0; i < 2; i++) {
            if (i >= mi) continue;
#pragma unroll
            for (int rg = 0; rg < 4; rg++) {
                int tl = mb * 64 + wm + i * 16 + q * 4 + rg;
                if (tl < LW) {
                    size_t rowoff = (size_t)(b * LW + tl) * H_ + h * HD_;
#pragma unroll
                    for (int j = 0; j < 6; j++)
                        ctx[rowoff + wn + j * 16 + r] = f2b(pacc[i][j][rg]);
                }
            }
        }
    }
}

// ---------------- fused residual add + LayerNorm (pure bf16 stream, f32 math) ----------------
__global__ __launch_bounds__(256) void add_ln_kernel(
    unsigned short* __restrict__ xb, const unsigned short* __restrict__ res,
    const float* __restrict__ sc, const float* __restrict__ bi)
{
    __shared__ float red[4];
    int row = blockIdx.x;
    int tid = threadIdx.x;
    size_t base = (size_t)row * H_;
    float v[3];
    float sum = 0.f;
#pragma unroll
    for (int i = 0; i < 3; i++) {
        int c = tid + i * 256;
        float t = b2f(xb[base + c]) + b2f(res[base + c]);
        v[i] = t; sum += t;
    }
    sum = block_sum(sum, red);
    float mean = sum * (1.f / H_);
    float var = 0.f;
#pragma unroll
    for (int i = 0; i < 3; i++) { float d = v[i] - mean; var += d * d; }
    var = block_sum(var, red);
    float inv = rsqrtf(var * (1.f / H_) + EPS_);
#pragma unroll
    for (int i = 0; i < 3; i++) {
        int c = tid + i * 256;
        xb[base + c] = f2b((v[i] - mean) * inv * sc[c] + bi[c]);
    }
}

// ---------------- R17: CLS attention core — coalesced K reads (8 lanes/key) ----------------
__global__ __launch_bounds__(256) void cls_attn_core2_kernel(
    const unsigned short* __restrict__ qrows,  // (64,H) bf16: rows 0..31 valid
    const unsigned short* __restrict__ qkvb,   // (MPAD,3H): cols 768..2303 = K,V (layer-1)
    const int* __restrict__ wvalid,
    unsigned short* __restrict__ ctxc)         // (64,H) bf16: rows 0..31 written
{
    __shared__ float qh[HD_];
    __shared__ float sr[160];
    __shared__ float ps[LW];
    __shared__ float red[4];
    int b = blockIdx.x, h = blockIdx.y;
    int tid = threadIdx.x, lane = tid & 63, wid = tid >> 6;
    if (tid < HD_) qh[tid] = b2f(qrows[(size_t)b * H_ + h * HD_ + tid]);
    __syncthreads();
    // scores: 8 lanes per key — each lane reads a contiguous 48B chunk of the 384B K-row
    int grp = tid >> 3, s8 = tid & 7;
#pragma unroll
    for (int p = 0; p < 5; p++) {
        int t = p * 32 + grp;
        float acc = 0.f;
        if (t < LW) {
            const unsigned short* kr = qkvb + (size_t)(b * LW + t) * (3 * H_) + H_ + h * HD_ + s8 * 24;
#pragma unroll
            for (int j = 0; j < 3; j++) {
                ushort8_t k8 = *(const ushort8_t*)(kr + j * 8);
#pragma unroll
                for (int jj = 0; jj < 8; jj++) acc += qh[s8 * 24 + j * 8 + jj] * b2f(k8[jj]);
            }
        }
        acc += __shfl_xor(acc, 1, 64);
        acc += __shfl_xor(acc, 2, 64);
        acc += __shfl_xor(acc, 4, 64);
        if (s8 == 0 && t < LW) {
            bool valid = (t == 0) || (wvalid[b * W_ + t - 1] != 0);
            sr[t] = valid ? acc * SCALE_ : -1e30f;
        }
    }
    __syncthreads();
    // block-wide softmax over 129
    float sc = (tid < LW) ? sr[tid] : -1e30f;
    float mx = wave_max(sc);
    if (lane == 0) red[wid] = mx;
    __syncthreads();
    mx = fmaxf(fmaxf(red[0], red[1]), fmaxf(red[2], red[3]));
    __syncthreads();
    float e = (tid < LW) ? __expf(sc - mx) : 0.f;
    float ssum = wave_sum(e);
    if (lane == 0) red[wid] = ssum;
    __syncthreads();
    ssum = (red[0] + red[1]) + (red[2] + red[3]);
    if (tid < LW) ps[tid] = e * (1.f / ssum);
    __syncthreads();
    // ctx: thread d; V reads coalesced across the wave (consecutive d per row)
    if (tid < HD_) {
        const unsigned short* vb = qkvb + (size_t)(b * LW) * (3 * H_) + 2 * H_ + h * HD_ + tid;
        float cx = 0.f;
#pragma unroll 8
        for (int t = 0; t < LW; t++)
            cx += ps[t] * b2f(vb[(size_t)t * (3 * H_)]);
        ctxc[(size_t)b * H_ + h * HD_ + tid] = f2b(cx);
    }
}

// ---------------- R15: out-proj result + CLS residual (from xb) + LN1 -> xc64 ----------------
__global__ __launch_bounds__(256) void cls_ln1_kernel(
    const unsigned short* __restrict__ proj,  // (64,H): out-proj output (incl bias)
    const unsigned short* __restrict__ xb,    // (MPAD,H): residual = CLS rows
    const float* __restrict__ sc, const float* __restrict__ bi,
    unsigned short* __restrict__ dst)         // (64,H): rows 0..31 written
{
    __shared__ float red[4];
    int b = blockIdx.x;
    int tid = threadIdx.x;
    float v[3]; float sum = 0.f;
#pragma unroll
    for (int i = 0; i < 3; i++) {
        int c = tid + i * 256;
        float t = b2f(proj[(size_t)b * H_ + c]) + b2f(xb[(size_t)(b * LW) * H_ + c]);
        v[i] = t; sum += t;
    }
    sum = block_sum(sum, red);
    float mean = sum * (1.f / H_);
    float var = 0.f;
#pragma unroll
    for (int i = 0; i < 3; i++) { float d = v[i] - mean; var += d * d; }
    var = block_sum(var, red);
    float inv = rsqrtf(var * (1.f / H_) + EPS_);
#pragma unroll
    for (int i = 0; i < 3; i++) {
        int c = tid + i * 256;
        dst[(size_t)b * H_ + c] = f2b((v[i] - mean) * inv * sc[c] + bi[c]);
    }
}

// ---------------- R14: final residual + LN2 + pooled + logits (32 rows) ----------------
__global__ __launch_bounds__(256) void cls_final_kernel(
    const unsigned short* __restrict__ proj,  // (64,H): ff2 output (incl bias)
    const unsigned short* __restrict__ resid, // (64,H): xc64
    const float* __restrict__ ln2s, const float* __restrict__ ln2b,
    const float* __restrict__ cls_w, const float* __restrict__ cls_b,
    float* __restrict__ out)
{
    __shared__ float red[4];
    __shared__ float lred[4][NLAB_];
    int b = blockIdx.x;
    int tid = threadIdx.x, lane = tid & 63, wid = tid >> 6;
    size_t base = (size_t)b * H_;
    float v[3]; float sum = 0.f;
#pragma unroll
    for (int i = 0; i < 3; i++) {
        int c = tid + i * 256;
        float t = b2f(proj[base + c]) + b2f(resid[base + c]);
        v[i] = t; sum += t;
    }
    sum = block_sum(sum, red);
    float mean = sum * (1.f / H_);
    float var = 0.f;
#pragma unroll
    for (int i = 0; i < 3; i++) { float d = v[i] - mean; var += d * d; }
    var = block_sum(var, red);
    float rinv = rsqrtf(var * (1.f / H_) + EPS_);
    float f3[3];
#pragma unroll
    for (int i = 0; i < 3; i++) {
        int c = tid + i * 256;
        f3[i] = (v[i] - mean) * rinv * ln2s[c] + ln2b[c];
        out[B_ * NLAB_ + b * H_ + c] = f3[i];
    }
    float l6[NLAB_] = {0.f, 0.f, 0.f, 0.f, 0.f, 0.f};
#pragma unroll
    for (int i = 0; i < 3; i++) {
        int c = tid + i * 256;
#pragma unroll
        for (int w = 0; w < NLAB_; w++) l6[w] += f3[i] * cls_w[w * H_ + c];
    }
#pragma unroll
    for (int w = 0; w < NLAB_; w++) l6[w] = wave_sum(l6[w]);
    if (lane == 0) {
#pragma unroll
        for (int w = 0; w < NLAB_; w++) lred[wid][w] = l6[w];
    }
    __syncthreads();
    if (tid < NLAB_)
        out[b * NLAB_ + tid] = lred[0][tid] + lred[1][tid] + lred[2][tid] + lred[3][tid] + cls_b[tid];
}

extern "C" void kernel_launch(void* const* d_in, const int* in_sizes, int n_in,
                              void* d_out, int out_size, void* d_ws, size_t ws_size,
                              hipStream_t stream) {
    const float* hidden = (const float*)d_in[0];
    const int*   wti    = (const int*)d_in[1];
    const int*   gmask  = (const int*)d_in[2];
    const int*   wvalid = (const int*)d_in[3];
    const float* qkv_w  = (const float*)d_in[4];
    const float* qkv_b  = (const float*)d_in[5];
    const float* out_w  = (const float*)d_in[6];
    const float* out_b  = (const float*)d_in[7];
    const float* ff1_w  = (const float*)d_in[8];
    const float* ff1_b  = (const float*)d_in[9];
    const float* ff2_w  = (const float*)d_in[10];
    const float* ff2_b  = (const float*)d_in[11];
    const float* ln1_s  = (const float*)d_in[12];
    const float* ln1_b  = (const float*)d_in[13];
    const float* ln2_s  = (const float*)d_in[14];
    const float* ln2_b  = (const float*)d_in[15];
    const float* cls_w  = (const float*)d_in[16];
    const float* cls_b  = (const float*)d_in[17];
    float* out = (float*)d_out;

    // workspace (all bf16): ~62 MB
    const size_t XSZ = (size_t)MPAD * H_;             // 3,244,032
    const size_t ASZ = (size_t)128 * TP * KP;         // 3,932,160
    const size_t R64 = (size_t)64 * H_;               // 49,152
    unsigned short* U    = (unsigned short*)d_ws;     // ASZ region: vtb/tmpb layer 0; CLS bufs layer 1
    unsigned short* vtb  = U;
    unsigned short* tmpb = U;                         // lifetimes disjoint
    unsigned short* qrows64 = U + 1 * R64;            // (64,H) q projections (rows 32..63 junk)
    unsigned short* ctxc  = U + 2 * R64;              // (64,H) attention context (rows 32..63 junk)
    unsigned short* xc64  = U + 3 * R64;              // (64,H) after LN1 (rows 32..63 junk)
    unsigned short* tmp64 = U + 4 * R64;              // (64,H) proj scratch
    unsigned short* h1c   = U + 5 * R64;              // (64,FF)
    unsigned short* xb   = U + ASZ;                   // XSZ
    unsigned short* ctxb = xb + XSZ;                  // XSZ
    unsigned short* qkvb = ctxb + XSZ;                // 3*XSZ (aliased: h1 MPAD*FF)
    unsigned short* wb   = qkvb + (size_t)MPAD * 3 * H_;     // 2*WL_SZ (both layers)

    // fused gather+pool + weight conversion (one launch)
    build_cvt_kernel<<<(LW + 3) * B_ + 2 * WL_SZ / 4 / 256, 256, 0, stream>>>(
        hidden, wti, gmask, wvalid, xb,
        (const float4*)qkv_w, (const float4*)out_w,
        (const float4*)ff1_w, (const float4*)ff2_w, (ushort4*)wb);

    const int GM = MPAD / 64;   // 66 m-blocks

    // ---------------- layer 0: full transformer block (R0/R7-verified configs) ----------------
    {
        unsigned short* wbl = wb;
        // qkv: R21 — bijective XCD swizzle (1188 blocks, SWZ=2)
        gemm_mfma<64, 128, 64, 0, 1, 2><<<dim3(3 * H_ / 128, GM), 256, 0, stream>>>(
            xb, wbl, qkv_b, qkvb, 3 * H_, H_, 3 * H_, H_);
        vt_kernel<<<128, 256, 0, stream>>>(qkvb, vtb);
        attn_fused_kernel<<<dim3(3, 128), 256, 0, stream>>>(qkvb, wvalid, vtb, ctxb);
        gemm_mfma<64, 64, 64, 0, 1, 1><<<dim3(H_ / 64, GM), 256, 0, stream>>>(
            ctxb, wbl + QW_SZ, out_b, tmpb, H_, H_, H_, H_);
        add_ln_kernel<<<M_, 256, 0, stream>>>(xb, tmpb, ln1_s, ln1_b);
        gemm_mfma<64, 128, 64, 1, 1, 1><<<dim3(FF_ / 128, GM), 256, 0, stream>>>(
            xb, wbl + QW_SZ + OW_SZ, ff1_b, qkvb, FF_, H_, FF_, H_);
        gemm_mfma<64, 64, 64, 0, 1, 1><<<dim3(H_ / 64, GM), 256, 0, stream>>>(
            qkvb, wbl + QW_SZ + OW_SZ + F1_SZ, ff2_b, tmpb, H_, FF_, H_, FF_);
        add_ln_kernel<<<M_, 256, 0, stream>>>(xb, tmpb, ln2_s, ln2_b);
    }

    // ---------------- layer 1: CLS-only path (only x[:,0,:] is read downstream) ----------------
    {
        unsigned short* wbl = wb + WL_SZ;
        // K,V for all rows + CLS q-proj, one launch (grid 13x66)
        gemm_kv_q_kernel<<<dim3(13, GM), 256, 0, stream>>>(
            xb, wbl + (size_t)H_ * H_, qkv_b + 3 * H_ + H_, qkvb + H_,
            wbl, qkv_b + 3 * H_, qrows64);
        // attention core (128 blocks: one per (b,h))
        cls_attn_core2_kernel<<<dim3(B_, NH_), 256, 0, stream>>>(
            qrows64, qkvb, wvalid, ctxc);
        // out-proj (R20: 64x64 tiles, 12 blocks)
        gemm_mfma<64, 64, 64, 0, 1, 0><<<dim3(H_ / 64, 1), 256, 0, stream>>>(
            ctxc, wbl + QW_SZ, out_b + H_, tmp64, H_, H_, H_, H_);
        // LN1 (residual read directly from xb CLS rows) -> xc64
        cls_ln1_kernel<<<B_, 256, 0, stream>>>(tmp64, xb, ln1_s + H_, ln1_b + H_, xc64);
        // ff1 + relu (R20: 64x64 tiles, 32 blocks)
        gemm_mfma<64, 64, 64, 1, 1, 0><<<dim3(FF_ / 64, 1), 256, 0, stream>>>(
            xc64, wbl + QW_SZ + OW_SZ, ff1_b + FF_, h1c, FF_, H_, FF_, H_);
        // ff2 (R20: 64x64 tiles, 12 blocks)
        gemm_mfma<64, 64, 64, 0, 1, 0><<<dim3(H_ / 64, 1), 256, 0, stream>>>(
            h1c, wbl + QW_SZ + OW_SZ + F1_SZ, ff2_b + H_, tmp64, H_, FF_, H_, FF_);
        // LN2 + pooled + logits
        cls_final_kernel<<<B_, 256, 0, stream>>>(tmp64, xc64, ln2_s + H_, ln2_b + H_,
                                                 cls_w, cls_b, out);
    }
    (void)in_sizes; (void)n_in; (void)out_size; (void)ws_size;
}